// Round 1
// baseline (1386.250 us; speedup 1.0000x reference)
//
#include <hip/hip_runtime.h>
#include <math.h>

#define B_ 8
#define L_ 1024
#define E_ 512
#define H_ 8
#define D_ 64
#define QSZ (B_*H_*L_*D_)          // 4,194,304 floats
#define TINYF 1.175494350822287508e-38f

// ws layout (floats):
//  Q  [B,H,L,D]      @ 0
//  K  [B,H,L,D]      @ QSZ
//  V  [B,H,L,D]      @ 2*QSZ
//  AE [B,L,E]        @ 3*QSZ   (unnormalized exp-part of attended)
//  AG [B,L,E]        @ 4*QSZ   (unnormalized gnorm-part of attended)
//  ACT[L,L]          @ 5*QSZ   (softmax(G))
//  SUMS: denom[8], gsums[8] @ 5*QSZ + L*L

__global__ void zero_sums_k(float* __restrict__ sums) {
  if (threadIdx.x < 16) sums[threadIdx.x] = 0.0f;
}

// C = x(8192x512) @ W(512x512)^T, scattered to (B,H,L,D); z picks Wq/Wk/Wv
__global__ __launch_bounds__(256) void proj_qkv_k(
    const float* __restrict__ x,
    const float* __restrict__ Wq, const float* __restrict__ Wk, const float* __restrict__ Wv,
    float* __restrict__ Q, float* __restrict__ K, float* __restrict__ V) {
  const float* W; float* O;
  if (blockIdx.z == 0)      { W = Wq; O = Q; }
  else if (blockIdx.z == 1) { W = Wk; O = K; }
  else                      { W = Wv; O = V; }
  const int i0 = blockIdx.x * 64;
  const int j0 = blockIdx.y * 64;
  __shared__ float As[64][20];
  __shared__ float Bs[64][20];
  const int t = threadIdx.x;
  const int tx = t & 15, ty = t >> 4;
  const int lr = t >> 2, lc = (t & 3) * 4;
  float acc[4][4] = {};
  for (int kk = 0; kk < E_; kk += 16) {
    *(float4*)&As[lr][lc] = *(const float4*)(x + (size_t)(i0 + lr) * E_ + kk + lc);
    *(float4*)&Bs[lr][lc] = *(const float4*)(W + (size_t)(j0 + lr) * E_ + kk + lc);
    __syncthreads();
#pragma unroll
    for (int k4 = 0; k4 < 4; ++k4) {
      float4 av[4], bv[4];
#pragma unroll
      for (int u = 0; u < 4; ++u) av[u] = *(const float4*)&As[ty + 16*u][k4*4];
#pragma unroll
      for (int v = 0; v < 4; ++v) bv[v] = *(const float4*)&Bs[tx + 16*v][k4*4];
#pragma unroll
      for (int u = 0; u < 4; ++u)
#pragma unroll
        for (int v = 0; v < 4; ++v) {
          acc[u][v] += av[u].x * bv[v].x;
          acc[u][v] += av[u].y * bv[v].y;
          acc[u][v] += av[u].z * bv[v].z;
          acc[u][v] += av[u].w * bv[v].w;
        }
    }
    __syncthreads();
  }
  const int h = j0 >> 6;
#pragma unroll
  for (int u = 0; u < 4; ++u) {
    const int i = i0 + ty + 16*u;
    const int b = i >> 10, l = i & 1023;
#pragma unroll
    for (int v = 0; v < 4; ++v) {
      const int d = tx + 16*v;
      O[(size_t)((b*H_ + h)*L_ + l)*D_ + d] = acc[u][v];
    }
  }
}

// row-softmax of G -> act
__global__ __launch_bounds__(256) void softmax_g_k(const float* __restrict__ G,
                                                   float* __restrict__ act) {
  const int row = blockIdx.x, t = threadIdx.x;
  __shared__ float red[256];
  const float* g = G + (size_t)row * L_;
  float m = -3.4e38f;
  for (int c = t; c < L_; c += 256) m = fmaxf(m, g[c]);
  red[t] = m; __syncthreads();
  for (int s = 128; s > 0; s >>= 1) { if (t < s) red[t] = fmaxf(red[t], red[t+s]); __syncthreads(); }
  m = red[0]; __syncthreads();
  float sum = 0.f;
  for (int c = t; c < L_; c += 256) sum += __expf(g[c] - m);
  red[t] = sum; __syncthreads();
  for (int s = 128; s > 0; s >>= 1) { if (t < s) red[t] += red[t+s]; __syncthreads(); }
  const float inv = 1.0f / red[0];
  for (int c = t; c < L_; c += 256) act[(size_t)row*L_ + c] = __expf(g[c] - m) * inv;
}

// gsums[b] = sum over valid q, valid k of act[q][k]
__global__ __launch_bounds__(256) void gsum_kk(const float* __restrict__ act,
                                               const int* __restrict__ mask,
                                               float* __restrict__ gsums) {
  const int q = blockIdx.x, b = blockIdx.y, t = threadIdx.x;
  if (mask[b*L_ + q] == 0) return;
  const float* a = act + (size_t)q * L_;
  const int* mk = mask + b*L_;
  float s = 0.f;
  for (int c = t; c < L_; c += 256) s += mk[c] ? a[c] : 0.f;
  __shared__ float red[256];
  red[t] = s; __syncthreads();
  for (int st = 128; st > 0; st >>= 1) { if (t < st) red[t] += red[t+st]; __syncthreads(); }
  if (t == 0) atomicAdd(gsums + b, red[0]);
}

// Flash-style: per (b,h,qtile): S = tanh(QK^T/8), E = exp(S-1)*mk; AE += E@V ;
// denom[b] += sum(E*mq). Normalization deferred to o_proj.
__global__ __launch_bounds__(256) void attn_k(
    const float* __restrict__ Q, const float* __restrict__ K, const float* __restrict__ V,
    const int* __restrict__ mask,
    float* __restrict__ AE, float* __restrict__ denom) {
  const int qt = blockIdx.x;
  const int bh = blockIdx.y;
  const int b = bh >> 3, h = bh & 7;
  const float* Qp = Q + (size_t)bh * L_ * D_;
  const float* Kp = K + (size_t)bh * L_ * D_;
  const float* Vp = V + (size_t)bh * L_ * D_;
  __shared__ float Qs[64][68];
  __shared__ float KEs[64][68];   // Ks during S-phase, then reused as E-tile
  __shared__ float VsT[64][68];   // V transposed: VsT[d][k]
  __shared__ float mks[64], mqs[64];
  __shared__ float red[256];
  const int t = threadIdx.x;
  const int tx = t & 15, ty = t >> 4;
  const int qr = t >> 4;           // 0..15
  const int qc = (t & 15) * 4;     // 0,4,..60
#pragma unroll
  for (int e = 0; e < 4; ++e) {
    const int r = e*16 + qr;
    *(float4*)&Qs[r][qc] = *(const float4*)(Qp + (size_t)(qt*64 + r)*D_ + qc);
  }
  if (t < 64) mqs[t] = mask[b*L_ + qt*64 + t] ? 1.0f : 0.0f;
  float ae[4][4] = {};
  float dsum = 0.f;
  for (int kt = 0; kt < 16; ++kt) {
    __syncthreads();  // prev PV done (and Qs/mqs visible on first iter)
#pragma unroll
    for (int e = 0; e < 4; ++e) {
      const int r = e*16 + qr;
      *(float4*)&KEs[r][qc] = *(const float4*)(Kp + (size_t)(kt*64 + r)*D_ + qc);
      float4 v4 = *(const float4*)(Vp + (size_t)(kt*64 + r)*D_ + qc);
      VsT[qc+0][r] = v4.x; VsT[qc+1][r] = v4.y; VsT[qc+2][r] = v4.z; VsT[qc+3][r] = v4.w;
    }
    if (t < 64) mks[t] = mask[b*L_ + kt*64 + t] ? 1.0f : 0.0f;
    __syncthreads();
    // S = Qs @ Ks^T
    float s[4][4] = {};
#pragma unroll
    for (int d4 = 0; d4 < 16; ++d4) {
      float4 qv[4], kv[4];
#pragma unroll
      for (int u = 0; u < 4; ++u) qv[u] = *(const float4*)&Qs[ty + 16*u][d4*4];
#pragma unroll
      for (int v = 0; v < 4; ++v) kv[v] = *(const float4*)&KEs[tx + 16*v][d4*4];
#pragma unroll
      for (int u = 0; u < 4; ++u)
#pragma unroll
        for (int v = 0; v < 4; ++v) {
          s[u][v] += qv[u].x*kv[v].x; s[u][v] += qv[u].y*kv[v].y;
          s[u][v] += qv[u].z*kv[v].z; s[u][v] += qv[u].w*kv[v].w;
        }
    }
    __syncthreads();  // all Ks reads done before overwriting as E
#pragma unroll
    for (int u = 0; u < 4; ++u)
#pragma unroll
      for (int v = 0; v < 4; ++v) {
        const int q = ty + 16*u, k = tx + 16*v;
        const float sc = tanhf(s[u][v] * 0.125f);
        const float ee = __expf(sc - 1.0f) * mks[k];
        KEs[q][k] = ee;
        dsum += ee * mqs[q];
      }
    __syncthreads();  // E visible
    // AE += E @ V
#pragma unroll
    for (int k4 = 0; k4 < 16; ++k4) {
      float4 ev[4], vv[4];
#pragma unroll
      for (int u = 0; u < 4; ++u) ev[u] = *(const float4*)&KEs[ty+16*u][k4*4];
#pragma unroll
      for (int v = 0; v < 4; ++v) vv[v] = *(const float4*)&VsT[tx+16*v][k4*4];
#pragma unroll
      for (int u = 0; u < 4; ++u)
#pragma unroll
        for (int v = 0; v < 4; ++v) {
          ae[u][v] += ev[u].x*vv[v].x; ae[u][v] += ev[u].y*vv[v].y;
          ae[u][v] += ev[u].z*vv[v].z; ae[u][v] += ev[u].w*vv[v].w;
        }
    }
  }
#pragma unroll
  for (int u = 0; u < 4; ++u)
#pragma unroll
    for (int v = 0; v < 4; ++v) {
      const int q = qt*64 + ty + 16*u;
      const int d = tx + 16*v;
      AE[(size_t)(b*L_ + q)*E_ + h*D_ + d] = ae[u][v];
    }
  red[t] = dsum; __syncthreads();
  for (int s2 = 128; s2 > 0; s2 >>= 1) { if (t < s2) red[t] += red[t+s2]; __syncthreads(); }
  if (t == 0) atomicAdd(denom + b, red[0]);
}

// AG[b, q, h*64+d] = sum_k act[q][k]*mk[b][k] * V[b,h,k,d]
__global__ __launch_bounds__(256) void gv_gemm_k(const float* __restrict__ act,
                                                 const int* __restrict__ mask,
                                                 const float* __restrict__ V,
                                                 float* __restrict__ AG) {
  const int q0 = blockIdx.x * 64;
  const int j0 = blockIdx.y * 64;
  const int b  = blockIdx.z;
  const int h  = j0 >> 6;
  const float* Vp = V + (size_t)(b*H_ + h) * L_ * D_;
  __shared__ float As[64][20];
  __shared__ float BsT[64][20];   // BsT[d][k16]
  const int t = threadIdx.x;
  const int tx = t & 15, ty = t >> 4;
  const int lr = t >> 2, lc = (t & 3) * 4;   // A load: row lr, cols lc..lc+3
  const int br = t >> 4, bc = (t & 15) * 4;  // B load: row br (k), cols bc..bc+3 (d)
  float acc[4][4] = {};
  for (int kk = 0; kk < L_; kk += 16) {
    float4 a4 = *(const float4*)(act + (size_t)(q0 + lr) * L_ + kk + lc);
    const int mb = b*L_ + kk + lc;
    a4.x = mask[mb+0] ? a4.x : 0.f;
    a4.y = mask[mb+1] ? a4.y : 0.f;
    a4.z = mask[mb+2] ? a4.z : 0.f;
    a4.w = mask[mb+3] ? a4.w : 0.f;
    *(float4*)&As[lr][lc] = a4;
    float4 v4 = *(const float4*)(Vp + (size_t)(kk + br)*D_ + bc);
    BsT[bc+0][br] = v4.x; BsT[bc+1][br] = v4.y; BsT[bc+2][br] = v4.z; BsT[bc+3][br] = v4.w;
    __syncthreads();
#pragma unroll
    for (int k4 = 0; k4 < 4; ++k4) {
      float4 av[4], bv[4];
#pragma unroll
      for (int u = 0; u < 4; ++u) av[u] = *(const float4*)&As[ty + 16*u][k4*4];
#pragma unroll
      for (int v = 0; v < 4; ++v) bv[v] = *(const float4*)&BsT[tx + 16*v][k4*4];
#pragma unroll
      for (int u = 0; u < 4; ++u)
#pragma unroll
        for (int v = 0; v < 4; ++v) {
          acc[u][v] += av[u].x * bv[v].x;
          acc[u][v] += av[u].y * bv[v].y;
          acc[u][v] += av[u].z * bv[v].z;
          acc[u][v] += av[u].w * bv[v].w;
        }
    }
    __syncthreads();
  }
#pragma unroll
  for (int u = 0; u < 4; ++u)
#pragma unroll
    for (int v = 0; v < 4; ++v) {
      const int q = q0 + ty + 16*u;
      const int d = tx + 16*v;
      AG[(size_t)(b*L_ + q)*E_ + j0 + d] = acc[u][v];
    }
}

// out = (mq * (c1*AE + c2*AG)) @ Wo^T
__global__ __launch_bounds__(256) void o_proj_k(const float* __restrict__ AE,
                                                const float* __restrict__ AG,
                                                const int* __restrict__ mask,
                                                const float* __restrict__ sums,
                                                const float* __restrict__ Wo,
                                                float* __restrict__ out) {
  const int i0 = blockIdx.x * 64;
  const int j0 = blockIdx.y * 64;
  const int b = i0 >> 10;
  const float c1 = 0.5f / fmaxf(sums[b],     TINYF);
  const float c2 = 0.5f / fmaxf(sums[8 + b], TINYF);
  __shared__ float As[64][20];
  __shared__ float Bs[64][20];
  const int t = threadIdx.x;
  const int tx = t & 15, ty = t >> 4;
  const int lr = t >> 2, lc = (t & 3) * 4;
  const float mq = mask[i0 + lr] ? 1.0f : 0.0f;
  float acc[4][4] = {};
  for (int kk = 0; kk < E_; kk += 16) {
    float4 a4 = *(const float4*)(AE + (size_t)(i0 + lr) * E_ + kk + lc);
    float4 g4 = *(const float4*)(AG + (size_t)(i0 + lr) * E_ + kk + lc);
    float4 m4;
    m4.x = mq * (c1*a4.x + c2*g4.x);
    m4.y = mq * (c1*a4.y + c2*g4.y);
    m4.z = mq * (c1*a4.z + c2*g4.z);
    m4.w = mq * (c1*a4.w + c2*g4.w);
    *(float4*)&As[lr][lc] = m4;
    *(float4*)&Bs[lr][lc] = *(const float4*)(Wo + (size_t)(j0 + lr) * E_ + kk + lc);
    __syncthreads();
#pragma unroll
    for (int k4 = 0; k4 < 4; ++k4) {
      float4 av[4], bv[4];
#pragma unroll
      for (int u = 0; u < 4; ++u) av[u] = *(const float4*)&As[ty + 16*u][k4*4];
#pragma unroll
      for (int v = 0; v < 4; ++v) bv[v] = *(const float4*)&Bs[tx + 16*v][k4*4];
#pragma unroll
      for (int u = 0; u < 4; ++u)
#pragma unroll
        for (int v = 0; v < 4; ++v) {
          acc[u][v] += av[u].x * bv[v].x;
          acc[u][v] += av[u].y * bv[v].y;
          acc[u][v] += av[u].z * bv[v].z;
          acc[u][v] += av[u].w * bv[v].w;
        }
    }
    __syncthreads();
  }
#pragma unroll
  for (int u = 0; u < 4; ++u)
#pragma unroll
    for (int v = 0; v < 4; ++v)
      out[(size_t)(i0 + ty + 16*u) * E_ + j0 + tx + 16*v] = acc[u][v];
}

extern "C" void kernel_launch(void* const* d_in, const int* in_sizes, int n_in,
                              void* d_out, int out_size, void* d_ws, size_t ws_size,
                              hipStream_t stream) {
  const float* x  = (const float*)d_in[0];
  const int*  mask= (const int*)d_in[1];
  const float* Wq = (const float*)d_in[2];
  const float* Wk = (const float*)d_in[3];
  const float* Wv = (const float*)d_in[4];
  const float* Wo = (const float*)d_in[5];
  const float* G  = (const float*)d_in[6];
  float* out = (float*)d_out;
  float* ws = (float*)d_ws;
  float* Q   = ws;
  float* K   = Q + QSZ;
  float* V   = K + QSZ;
  float* AE  = V + QSZ;
  float* AG  = AE + QSZ;
  float* ACT = AG + QSZ;
  float* SUMS = ACT + (size_t)L_ * L_;   // denom[8], gsums[8]

  zero_sums_k<<<1, 64, 0, stream>>>(SUMS);
  proj_qkv_k<<<dim3(128, 8, 3), 256, 0, stream>>>(x, Wq, Wk, Wv, Q, K, V);
  softmax_g_k<<<1024, 256, 0, stream>>>(G, ACT);
  gsum_kk<<<dim3(1024, 8), 256, 0, stream>>>(ACT, mask, SUMS + 8);
  attn_k<<<dim3(16, 64), 256, 0, stream>>>(Q, K, V, mask, AE, SUMS);
  gv_gemm_k<<<dim3(16, 8, 8), 256, 0, stream>>>(ACT, mask, V, AG);
  o_proj_k<<<dim3(128, 8), 256, 0, stream>>>(AE, AG, mask, SUMS, Wo, out);
}

// Round 2
// 300.697 us; speedup vs baseline: 4.6101x; 4.6101x over previous
//
#include <hip/hip_runtime.h>
#include <math.h>

#define B_ 8
#define L_ 1024
#define E_ 512
#define H_ 8
#define D_ 64
#define QSZ (B_*H_*L_*D_)          // 4,194,304 elements
#define TINYF 1.175494350822287508e-38f

typedef unsigned short u16;
typedef __attribute__((ext_vector_type(8))) short bfrag;   // 8 bf16 (4 VGPRs)
typedef __attribute__((ext_vector_type(4))) float ffrag;   // 4 fp32 acc
typedef __attribute__((ext_vector_type(4))) short vshort4;

__device__ __forceinline__ u16 f2b(float f) {
  unsigned u = __float_as_uint(f);
  u += 0x7fffu + ((u >> 16) & 1u);           // RNE
  return (u16)(u >> 16);
}

__device__ __forceinline__ bfrag cvt8v(const float* __restrict__ src) {
  float4 a = *(const float4*)src;
  float4 b = *(const float4*)(src + 4);
  bfrag r;
  r[0]=(short)f2b(a.x); r[1]=(short)f2b(a.y); r[2]=(short)f2b(a.z); r[3]=(short)f2b(a.w);
  r[4]=(short)f2b(b.x); r[5]=(short)f2b(b.y); r[6]=(short)f2b(b.z); r[7]=(short)f2b(b.w);
  return r;
}

// ws layout:
//  Qb [B,H,L,D] u16 ; Kb [B,H,L,D] u16 ; Vtb [B,H,D,L] u16 (pre-masked by key mask)
//  AE [B,L,E] f32 ; AG [B,L,E] f32 ; ACT [L,L] f32 ; SUMS: denom[8], gsums[8]

__global__ void zero_sums_k(float* __restrict__ sums) {
  if (threadIdx.x < 16) sums[threadIdx.x] = 0.0f;
}

// ---- QKV projection: bf16 MFMA, fp32 inputs cast at staging -----------------
__global__ __launch_bounds__(256) void proj_qkv_k(
    const float* __restrict__ x, const float* __restrict__ Wq,
    const float* __restrict__ Wk, const float* __restrict__ Wv,
    const int* __restrict__ mask,
    u16* __restrict__ Qb, u16* __restrict__ Kb, u16* __restrict__ Vtb) {
  const float* W = (blockIdx.z == 0) ? Wq : (blockIdx.z == 1) ? Wk : Wv;
  const int m0 = blockIdx.x * 64;          // row tile in [0,8192)
  const int h  = blockIdx.y;               // n tile = head
  __shared__ u16 As[64*64];
  __shared__ u16 Bs[64*64];
  const int t = threadIdx.x;
  const int w = t >> 6, lane = t & 63;
  const int l15 = lane & 15, quad = lane >> 4;
  ffrag acc[4] = {{0,0,0,0},{0,0,0,0},{0,0,0,0},{0,0,0,0}};
  for (int kk = 0; kk < E_; kk += 64) {
    __syncthreads();
#pragma unroll
    for (int i = 0; i < 2; ++i) {
      int c = t + i*256, row = c >> 3, ck = c & 7;
      int sw = row*64 + ((ck ^ (row & 7)) << 3);          // XOR-swizzled chunk
      *(bfrag*)&As[sw] = cvt8v(x + (size_t)(m0 + row)*E_ + kk + ck*8);
      *(bfrag*)&Bs[sw] = cvt8v(W + (size_t)(h*64 + row)*E_ + kk + ck*8);
    }
    __syncthreads();
#pragma unroll
    for (int s = 0; s < 2; ++s) {
      const int ar = w*16 + l15;
      bfrag af = *(const bfrag*)&As[ar*64 + (((quad + 4*s) ^ (ar & 7)) << 3)];
#pragma unroll
      for (int nb = 0; nb < 4; ++nb) {
        const int br = nb*16 + l15;
        bfrag bf = *(const bfrag*)&Bs[br*64 + (((quad + 4*s) ^ (br & 7)) << 3)];
        acc[nb] = __builtin_amdgcn_mfma_f32_16x16x32_bf16(af, bf, acc[nb], 0, 0, 0);
      }
    }
  }
#pragma unroll
  for (int nb = 0; nb < 4; ++nb) {
    const int d = nb*16 + l15;
#pragma unroll
    for (int r = 0; r < 4; ++r) {
      const int i = m0 + w*16 + quad*4 + r;
      const int b = i >> 10, l = i & 1023;
      if (blockIdx.z == 0)
        Qb[((size_t)(b*H_ + h)*L_ + l)*D_ + d] = f2b(acc[nb][r]);
      else if (blockIdx.z == 1)
        Kb[((size_t)(b*H_ + h)*L_ + l)*D_ + d] = f2b(acc[nb][r]);
      else {
        const float mv = mask[b*L_ + l] ? 1.0f : 0.0f;    // fold key mask into V
        Vtb[((size_t)(b*H_ + h)*D_ + d)*L_ + l] = f2b(acc[nb][r] * mv);
      }
    }
  }
}

// ---- softmax(G) rows --------------------------------------------------------
__global__ __launch_bounds__(256) void softmax_g_k(const float* __restrict__ G,
                                                   float* __restrict__ act) {
  const int row = blockIdx.x, t = threadIdx.x;
  __shared__ float red[256];
  const float* g = G + (size_t)row * L_;
  float m = -3.4e38f;
  for (int c = t; c < L_; c += 256) m = fmaxf(m, g[c]);
  red[t] = m; __syncthreads();
  for (int s = 128; s > 0; s >>= 1) { if (t < s) red[t] = fmaxf(red[t], red[t+s]); __syncthreads(); }
  m = red[0]; __syncthreads();
  float sum = 0.f;
  for (int c = t; c < L_; c += 256) sum += __expf(g[c] - m);
  red[t] = sum; __syncthreads();
  for (int s = 128; s > 0; s >>= 1) { if (t < s) red[t] += red[t+s]; __syncthreads(); }
  const float inv = 1.0f / red[0];
  for (int c = t; c < L_; c += 256) act[(size_t)row*L_ + c] = __expf(g[c] - m) * inv;
}

__global__ __launch_bounds__(256) void gsum_kk(const float* __restrict__ act,
                                               const int* __restrict__ mask,
                                               float* __restrict__ gsums) {
  const int q = blockIdx.x, b = blockIdx.y, t = threadIdx.x;
  if (mask[b*L_ + q] == 0) return;
  const float* a = act + (size_t)q * L_;
  const int* mk = mask + b*L_;
  float s = 0.f;
  for (int c = t; c < L_; c += 256) s += mk[c] ? a[c] : 0.f;
  __shared__ float red[256];
  red[t] = s; __syncthreads();
  for (int st = 128; st > 0; st >>= 1) { if (t < st) red[t] += red[t+st]; __syncthreads(); }
  if (t == 0) atomicAdd(gsums + b, red[0]);
}

// ---- fused tanh-attention: S^T = K.Q^T (MFMA), E = exp(tanh-1) in C-layout
//      (4 consecutive k per lane -> packed b64 LDS writes), AE += E.V (MFMA) --
__global__ __launch_bounds__(256) void attn_k(
    const u16* __restrict__ Qb, const u16* __restrict__ Kb,
    const u16* __restrict__ Vtb, const int* __restrict__ mask,
    float* __restrict__ AE, float* __restrict__ denom) {
  const int qt = blockIdx.x;
  const int bh = blockIdx.y;
  const int b = bh >> 3, h = bh & 7;
  __shared__ u16 Qs[64*64];
  __shared__ u16 Ks[64*64];
  __shared__ u16 Vs[64*64];       // Vt tile: [d][k]
  __shared__ u16 Es[4*16*64];     // per-wave E tile [q16][k64]
  __shared__ float mks[64];
  __shared__ float red[256];
  const int t = threadIdx.x;
  const int w = t >> 6, lane = t & 63;
  const int l15 = lane & 15, quad = lane >> 4;

  const u16* Qg = Qb + ((size_t)bh * L_ + qt*64) * D_;
  const u16* Kg = Kb + (size_t)bh * L_ * D_;
  const u16* Vg = Vtb + (size_t)bh * D_ * L_;

#pragma unroll
  for (int i = 0; i < 2; ++i) {
    int c = t + i*256, row = c >> 3, ck = c & 7;
    *(bfrag*)&Qs[row*64 + ((ck ^ (row & 7)) << 3)] = *(const bfrag*)(Qg + c*8);
  }
  const float mq = mask[b*L_ + qt*64 + w*16 + l15] ? 1.0f : 0.0f;

  ffrag acc[4] = {{0,0,0,0},{0,0,0,0},{0,0,0,0},{0,0,0,0}};
  float dsum = 0.0f;

  for (int kt = 0; kt < 16; ++kt) {
    __syncthreads();
#pragma unroll
    for (int i = 0; i < 2; ++i) {
      int c = t + i*256, row = c >> 3, ck = c & 7;
      int sw = row*64 + ((ck ^ (row & 7)) << 3);
      *(bfrag*)&Ks[sw] = *(const bfrag*)(Kg + (size_t)kt*4096 + c*8);
      *(bfrag*)&Vs[sw] = *(const bfrag*)(Vg + (size_t)row*L_ + kt*64 + ck*8);
    }
    if (t < 64) mks[t] = mask[b*L_ + kt*64 + t] ? 1.0f : 0.0f;
    __syncthreads();

    // S^T tile: A = K rows (m = k-dim), B = Q rows (n = q-dim, wave's 16 cols)
    ffrag st[4] = {{0,0,0,0},{0,0,0,0},{0,0,0,0},{0,0,0,0}};
#pragma unroll
    for (int s = 0; s < 2; ++s) {
      const int qrow = w*16 + l15;
      bfrag bq = *(const bfrag*)&Qs[qrow*64 + (((quad + 4*s) ^ (qrow & 7)) << 3)];
#pragma unroll
      for (int mb = 0; mb < 4; ++mb) {
        const int krow = mb*16 + l15;
        bfrag ak = *(const bfrag*)&Ks[krow*64 + (((quad + 4*s) ^ (krow & 7)) << 3)];
        st[mb] = __builtin_amdgcn_mfma_f32_16x16x32_bf16(ak, bq, st[mb], 0, 0, 0);
      }
    }

    // E = exp(tanh(s/8)-1) = exp(-2/(e^(s/4)+1)); lane holds 4 consecutive k
#pragma unroll
    for (int mb = 0; mb < 4; ++mb) {
      vshort4 pack;
      float lsum = 0.0f;
#pragma unroll
      for (int r = 0; r < 4; ++r) {
        const int k = mb*16 + quad*4 + r;
        const float xv = st[mb][r] * 0.25f;
        const float ee = __expf(__fdividef(-2.0f, __expf(xv) + 1.0f));
        pack[r] = (short)f2b(ee);
        lsum += ee * mks[k];
      }
      dsum += lsum * mq;
      const int col = mb*16 + quad*4;
      const int cks = (col >> 3) ^ (l15 & 7);
      *(vshort4*)&Es[w*1024 + l15*64 + cks*8 + (col & 7)] = pack;
    }

    // AE += E @ V  (A = Es rows (m=q), B = Vt rows (n=d))
#pragma unroll
    for (int s = 0; s < 2; ++s) {
      bfrag ea = *(const bfrag*)&Es[w*1024 + l15*64 + (((quad + 4*s) ^ (l15 & 7)) << 3)];
#pragma unroll
      for (int nb = 0; nb < 4; ++nb) {
        const int drow = nb*16 + l15;
        bfrag bv = *(const bfrag*)&Vs[drow*64 + (((quad + 4*s) ^ (drow & 7)) << 3)];
        acc[nb] = __builtin_amdgcn_mfma_f32_16x16x32_bf16(ea, bv, acc[nb], 0, 0, 0);
      }
    }
  }

#pragma unroll
  for (int nb = 0; nb < 4; ++nb)
#pragma unroll
    for (int r = 0; r < 4; ++r) {
      const int q = qt*64 + w*16 + quad*4 + r;
      const int d = nb*16 + l15;
      AE[((size_t)b*L_ + q)*E_ + h*64 + d] = acc[nb][r];
    }

  red[t] = dsum; __syncthreads();
  for (int s2 = 128; s2 > 0; s2 >>= 1) { if (t < s2) red[t] += red[t+s2]; __syncthreads(); }
  if (t == 0) atomicAdd(denom + b, red[0]);
}

// ---- AG = act @ (masked V), via Vt rows as pre-transposed B -----------------
__global__ __launch_bounds__(256) void gv_k(const float* __restrict__ act,
                                            const u16* __restrict__ Vtb,
                                            float* __restrict__ AG) {
  const int q0 = blockIdx.x * 64;
  const int h  = blockIdx.y;
  const int b  = blockIdx.z;
  __shared__ u16 As[64*64];
  __shared__ u16 Bs[64*64];
  const int t = threadIdx.x;
  const int w = t >> 6, lane = t & 63;
  const int l15 = lane & 15, quad = lane >> 4;
  const u16* Vg = Vtb + (size_t)(b*H_ + h) * D_ * L_;
  ffrag acc[4] = {{0,0,0,0},{0,0,0,0},{0,0,0,0},{0,0,0,0}};
  for (int kk = 0; kk < L_; kk += 64) {
    __syncthreads();
#pragma unroll
    for (int i = 0; i < 2; ++i) {
      int c = t + i*256, row = c >> 3, ck = c & 7;
      int sw = row*64 + ((ck ^ (row & 7)) << 3);
      *(bfrag*)&As[sw] = cvt8v(act + (size_t)(q0 + row)*L_ + kk + ck*8);
      *(bfrag*)&Bs[sw] = *(const bfrag*)(Vg + (size_t)row*L_ + kk + ck*8);
    }
    __syncthreads();
#pragma unroll
    for (int s = 0; s < 2; ++s) {
      const int ar = w*16 + l15;
      bfrag af = *(const bfrag*)&As[ar*64 + (((quad + 4*s) ^ (ar & 7)) << 3)];
#pragma unroll
      for (int nb = 0; nb < 4; ++nb) {
        const int br = nb*16 + l15;
        bfrag bf = *(const bfrag*)&Bs[br*64 + (((quad + 4*s) ^ (br & 7)) << 3)];
        acc[nb] = __builtin_amdgcn_mfma_f32_16x16x32_bf16(af, bf, acc[nb], 0, 0, 0);
      }
    }
  }
#pragma unroll
  for (int nb = 0; nb < 4; ++nb)
#pragma unroll
    for (int r = 0; r < 4; ++r) {
      const int q = q0 + w*16 + quad*4 + r;
      AG[((size_t)b*L_ + q)*E_ + h*64 + nb*16 + l15] = acc[nb][r];
    }
}

// ---- out = (mq*(c1*AE + c2*AG)) @ Wo^T --------------------------------------
__global__ __launch_bounds__(256) void o_proj_k(
    const float* __restrict__ AE, const float* __restrict__ AG,
    const int* __restrict__ mask, const float* __restrict__ sums,
    const float* __restrict__ Wo, float* __restrict__ out) {
  const int m0 = blockIdx.x * 64;
  const int n0 = blockIdx.y * 64;
  const int b  = m0 >> 10;
  const float c1 = 0.5f / fmaxf(sums[b],      TINYF);
  const float c2 = 0.5f / fmaxf(sums[8 + b],  TINYF);
  __shared__ u16 As[64*64];
  __shared__ u16 Bs[64*64];
  const int t = threadIdx.x;
  const int w = t >> 6, lane = t & 63;
  const int l15 = lane & 15, quad = lane >> 4;
  ffrag acc[4] = {{0,0,0,0},{0,0,0,0},{0,0,0,0},{0,0,0,0}};
  for (int kk = 0; kk < E_; kk += 64) {
    __syncthreads();
#pragma unroll
    for (int i = 0; i < 2; ++i) {
      int c = t + i*256, row = c >> 3, ck = c & 7;
      int sw = row*64 + ((ck ^ (row & 7)) << 3);
      const float mqv = mask[b*L_ + ((m0 + row) & 1023)] ? 1.0f : 0.0f;
      const float* ae = AE + (size_t)(m0 + row)*E_ + kk + ck*8;
      const float* ag = AG + (size_t)(m0 + row)*E_ + kk + ck*8;
      float4 a0 = *(const float4*)ae, a1 = *(const float4*)(ae + 4);
      float4 g0 = *(const float4*)ag, g1 = *(const float4*)(ag + 4);
      bfrag r;
      r[0]=(short)f2b(mqv*(c1*a0.x + c2*g0.x)); r[1]=(short)f2b(mqv*(c1*a0.y + c2*g0.y));
      r[2]=(short)f2b(mqv*(c1*a0.z + c2*g0.z)); r[3]=(short)f2b(mqv*(c1*a0.w + c2*g0.w));
      r[4]=(short)f2b(mqv*(c1*a1.x + c2*g1.x)); r[5]=(short)f2b(mqv*(c1*a1.y + c2*g1.y));
      r[6]=(short)f2b(mqv*(c1*a1.z + c2*g1.z)); r[7]=(short)f2b(mqv*(c1*a1.w + c2*g1.w));
      *(bfrag*)&As[sw] = r;
      *(bfrag*)&Bs[sw] = cvt8v(Wo + (size_t)(n0 + row)*E_ + kk + ck*8);
    }
    __syncthreads();
#pragma unroll
    for (int s = 0; s < 2; ++s) {
      const int ar = w*16 + l15;
      bfrag af = *(const bfrag*)&As[ar*64 + (((quad + 4*s) ^ (ar & 7)) << 3)];
#pragma unroll
      for (int nb = 0; nb < 4; ++nb) {
        const int br = nb*16 + l15;
        bfrag bf = *(const bfrag*)&Bs[br*64 + (((quad + 4*s) ^ (br & 7)) << 3)];
        acc[nb] = __builtin_amdgcn_mfma_f32_16x16x32_bf16(af, bf, acc[nb], 0, 0, 0);
      }
    }
  }
#pragma unroll
  for (int nb = 0; nb < 4; ++nb)
#pragma unroll
    for (int r = 0; r < 4; ++r)
      out[(size_t)(m0 + w*16 + quad*4 + r)*E_ + n0 + nb*16 + l15] = acc[nb][r];
}

extern "C" void kernel_launch(void* const* d_in, const int* in_sizes, int n_in,
                              void* d_out, int out_size, void* d_ws, size_t ws_size,
                              hipStream_t stream) {
  const float* x  = (const float*)d_in[0];
  const int* mask = (const int*)d_in[1];
  const float* Wq = (const float*)d_in[2];
  const float* Wk = (const float*)d_in[3];
  const float* Wv = (const float*)d_in[4];
  const float* Wo = (const float*)d_in[5];
  const float* G  = (const float*)d_in[6];
  float* out = (float*)d_out;

  u16* Qb  = (u16*)d_ws;
  u16* Kb  = Qb + QSZ;
  u16* Vtb = Kb + QSZ;
  float* AE  = (float*)(Vtb + QSZ);
  float* AG  = AE + (size_t)B_*L_*E_;
  float* ACT = AG + (size_t)B_*L_*E_;
  float* SUMS = ACT + (size_t)L_*L_;   // denom[8], gsums[8]

  zero_sums_k<<<1, 64, 0, stream>>>(SUMS);
  proj_qkv_k<<<dim3(128, 8, 3), 256, 0, stream>>>(x, Wq, Wk, Wv, mask, Qb, Kb, Vtb);
  softmax_g_k<<<1024, 256, 0, stream>>>(G, ACT);
  gsum_kk<<<dim3(1024, 8), 256, 0, stream>>>(ACT, mask, SUMS + 8);
  attn_k<<<dim3(16, 64), 256, 0, stream>>>(Qb, Kb, Vtb, mask, AE, SUMS);
  gv_k<<<dim3(16, 8, 8), 256, 0, stream>>>(ACT, Vtb, AG);
  o_proj_k<<<dim3(128, 8), 256, 0, stream>>>(AE, AG, mask, SUMS, Wo, out);
}

// Round 3
// 229.564 us; speedup vs baseline: 6.0386x; 1.3099x over previous
//
#include <hip/hip_runtime.h>
#include <math.h>

#define B_ 8
#define L_ 1024
#define E_ 512
#define H_ 8
#define D_ 64
#define QSZ (B_*H_*L_*D_)          // 4,194,304 elements
#define TINYF 1.175494350822287508e-38f

typedef unsigned short u16;
typedef __attribute__((ext_vector_type(8))) short bfrag;   // 8 bf16 (4 VGPRs)
typedef __attribute__((ext_vector_type(4))) float ffrag;   // 4 fp32 acc
typedef __attribute__((ext_vector_type(4))) short vshort4;

__device__ __forceinline__ u16 f2b(float f) {
  unsigned u = __float_as_uint(f);
  u += 0x7fffu + ((u >> 16) & 1u);           // RNE
  return (u16)(u >> 16);
}
__device__ __forceinline__ unsigned pk2(float a, float b) {  // lo=rne(a), hi=rne(b)
  unsigned ua = __float_as_uint(a); ua += 0x7fffu + ((ua >> 16) & 1u);
  unsigned ub = __float_as_uint(b); ub += 0x7fffu + ((ub >> 16) & 1u);
  return (ua >> 16) | (ub & 0xffff0000u);
}
__device__ __forceinline__ float b2f(unsigned h) { return __uint_as_float(h << 16); }

__device__ __forceinline__ bfrag cvt8v(const float* __restrict__ src) {
  float4 a = *(const float4*)src;
  float4 b = *(const float4*)(src + 4);
  bfrag r;
  r[0]=(short)f2b(a.x); r[1]=(short)f2b(a.y); r[2]=(short)f2b(a.z); r[3]=(short)f2b(a.w);
  r[4]=(short)f2b(b.x); r[5]=(short)f2b(b.y); r[6]=(short)f2b(b.z); r[7]=(short)f2b(b.w);
  return r;
}

// async global->LDS, 16B per lane; lds base must be wave-uniform (HW adds lane*16)
__device__ __forceinline__ void gll16(const void* g, void* l) {
  __builtin_amdgcn_global_load_lds(
      (const __attribute__((address_space(1))) void*)g,
      (__attribute__((address_space(3))) void*)l, 16, 0, 0);
}

// ws: xb[8192*512]u16, Wb[2048*512]u16 (Wq,Wk,Wv,Wo stacked), Qb/Kb[B,H,L,D]u16,
//     Vtb[B,H,D,L]u16 (pre-masked), actb[1024*1024]u16, AE[B,L,E]f32,
//     Cb[8192*512]u16, R[1024*8]f32, SUMS{denom[8],gsums[8]}f32

// ---- prep: fp32->bf16 conversions + zero sums -------------------------------
__global__ __launch_bounds__(256) void prep_k(
    const float* __restrict__ x, const float* __restrict__ Wq,
    const float* __restrict__ Wk, const float* __restrict__ Wv,
    const float* __restrict__ Wo, u16* __restrict__ xb, u16* __restrict__ Wb,
    float* __restrict__ sums) {
  const int bid = blockIdx.x, t = threadIdx.x;
  if (bid == 0 && t < 16) sums[t] = 0.0f;
  if (bid < 2048) {
    size_t c = (size_t)bid * 256 + t;                  // 8-float chunk of x
    *(bfrag*)&xb[c * 8] = cvt8v(x + c * 8);
  } else {
    const int c2 = bid - 2048;                         // 0..511
    const float* src = (c2 < 128) ? Wq : (c2 < 256) ? Wk : (c2 < 384) ? Wv : Wo;
    const size_t base = (size_t)(c2 >> 7) * 262144;    // u16 offset per matrix
    const size_t cc = (size_t)(c2 & 127) * 256 + t;    // chunk within matrix
    *(bfrag*)&Wb[base + cc * 8] = cvt8v(src + cc * 8);
  }
}

// ---- softmax(G) rows -> actb bf16, plus masked row-dots R[q][b] -------------
__global__ __launch_bounds__(256) void softmax_g_k(
    const float* __restrict__ G, const int* __restrict__ mask,
    u16* __restrict__ actb, float* __restrict__ R) {
  const int q = blockIdx.x, t = threadIdx.x;
  const int w = t >> 6, lane = t & 63;
  __shared__ float sred[8];
  __shared__ float rred[4][8];
  float4 g4 = ((const float4*)(G + (size_t)q * 1024))[t];
  float m = fmaxf(fmaxf(g4.x, g4.y), fmaxf(g4.z, g4.w));
#pragma unroll
  for (int off = 32; off > 0; off >>= 1) m = fmaxf(m, __shfl_down(m, off));
  if (lane == 0) sred[w] = m;
  __syncthreads();
  m = fmaxf(fmaxf(sred[0], sred[1]), fmaxf(sred[2], sred[3]));
  float e0 = __expf(g4.x - m), e1 = __expf(g4.y - m);
  float e2 = __expf(g4.z - m), e3 = __expf(g4.w - m);
  float s = e0 + e1 + e2 + e3;
#pragma unroll
  for (int off = 32; off > 0; off >>= 1) s += __shfl_down(s, off);
  if (lane == 0) sred[4 + w] = s;
  __syncthreads();
  const float inv = 1.0f / (sred[4] + sred[5] + sred[6] + sred[7]);
  const unsigned p0 = pk2(e0 * inv, e1 * inv);
  const unsigned p1 = pk2(e2 * inv, e3 * inv);
  *(uint2*)&actb[(size_t)q * 1024 + t * 4] = make_uint2(p0, p1);
  // bf16-rounded values (consistent with AG numerator path)
  const float r0 = b2f(p0 & 0xffffu), r1 = b2f(p0 >> 16);
  const float r2 = b2f(p1 & 0xffffu), r3 = b2f(p1 >> 16);
  float rd[8];
#pragma unroll
  for (int b = 0; b < 8; ++b) {
    const int* mkp = mask + b * 1024 + t * 4;
    rd[b] = (mkp[0] ? r0 : 0.f) + (mkp[1] ? r1 : 0.f) +
            (mkp[2] ? r2 : 0.f) + (mkp[3] ? r3 : 0.f);
#pragma unroll
    for (int off = 32; off > 0; off >>= 1) rd[b] += __shfl_down(rd[b], off);
  }
  if (lane == 0)
#pragma unroll
    for (int b = 0; b < 8; ++b) rred[w][b] = rd[b];
  __syncthreads();
  if (t < 8) R[q * 8 + t] = rred[0][t] + rred[1][t] + rred[2][t] + rred[3][t];
}

// ---- gsums[b] = sum_q mq * R[q][b] ------------------------------------------
__global__ __launch_bounds__(256) void gsum_reduce_k(
    const float* __restrict__ R, const int* __restrict__ mask,
    float* __restrict__ sums) {
  const int t = threadIdx.x, w = t >> 6, lane = t & 63;
  __shared__ float rr[4][8];
  float acc[8] = {0,0,0,0,0,0,0,0};
  for (int q = t; q < 1024; q += 256)
#pragma unroll
    for (int b = 0; b < 8; ++b)
      if (mask[b * 1024 + q]) acc[b] += R[q * 8 + b];
#pragma unroll
  for (int b = 0; b < 8; ++b) {
#pragma unroll
    for (int off = 32; off > 0; off >>= 1) acc[b] += __shfl_down(acc[b], off);
  }
  if (lane == 0)
#pragma unroll
    for (int b = 0; b < 8; ++b) rr[w][b] = acc[b];
  __syncthreads();
  if (t < 8) sums[8 + t] = rr[0][t] + rr[1][t] + rr[2][t] + rr[3][t];
}

// ---- QKV projection: GLL GEMM 128x64, xb @ Wb[0:1536]^T ---------------------
__global__ __launch_bounds__(256) void proj_k(
    const u16* __restrict__ xb, const u16* __restrict__ Wb,
    const int* __restrict__ mask,
    u16* __restrict__ Qb, u16* __restrict__ Kb, u16* __restrict__ Vtb) {
  const int m0 = blockIdx.x * 128;
  const int n0 = blockIdx.y * 64;
  __shared__ u16 As[128 * 64];
  __shared__ u16 Bs[64 * 64];
  const int t = threadIdx.x, w = t >> 6, lane = t & 63;
  const int l15 = lane & 15, quad = lane >> 4;
  const ffrag fz = {0.f, 0.f, 0.f, 0.f};
  ffrag acc[2][4];
#pragma unroll
  for (int am = 0; am < 2; ++am)
#pragma unroll
    for (int bn = 0; bn < 4; ++bn) acc[am][bn] = fz;

  for (int kk = 0; kk < 512; kk += 64) {
    __syncthreads();
#pragma unroll
    for (int j = 0; j < 4; ++j) {
      const int c = w * 256 + j * 64 + lane;
      gll16(xb + (size_t)(m0 + (c >> 3)) * 512 + kk + (c & 7) * 8,
            &As[(size_t)(w * 256 + j * 64) * 8]);
    }
#pragma unroll
    for (int j = 0; j < 2; ++j) {
      const int c = w * 128 + j * 64 + lane;
      gll16(Wb + (size_t)(n0 + (c >> 3)) * 512 + kk + (c & 7) * 8,
            &Bs[(size_t)(w * 128 + j * 64) * 8]);
    }
    __syncthreads();
#pragma unroll
    for (int s = 0; s < 2; ++s) {
      bfrag a0 = *(const bfrag*)&As[(w * 32 + l15) * 64 + (quad + 4 * s) * 8];
      bfrag a1 = *(const bfrag*)&As[(w * 32 + 16 + l15) * 64 + (quad + 4 * s) * 8];
#pragma unroll
      for (int bn = 0; bn < 4; ++bn) {
        bfrag bb = *(const bfrag*)&Bs[(bn * 16 + l15) * 64 + (quad + 4 * s) * 8];
        acc[0][bn] = __builtin_amdgcn_mfma_f32_16x16x32_bf16(a0, bb, acc[0][bn], 0, 0, 0);
        acc[1][bn] = __builtin_amdgcn_mfma_f32_16x16x32_bf16(a1, bb, acc[1][bn], 0, 0, 0);
      }
    }
  }
  const int z = n0 >> 9;
  const int c0 = n0 & 511;
#pragma unroll
  for (int am = 0; am < 2; ++am) {
    const int mbase = m0 + w * 32 + am * 16 + quad * 4;
    const int b = mbase >> 10, l0 = mbase & 1023;
#pragma unroll
    for (int bn = 0; bn < 4; ++bn) {
      const int nc = c0 + bn * 16 + l15;
      const int h = nc >> 6, d = nc & 63;
      if (z == 0) {
        u16* dst = Qb + ((size_t)(b * 8 + h) * 1024 + l0) * 64 + d;
#pragma unroll
        for (int r = 0; r < 4; ++r) dst[(size_t)r * 64] = f2b(acc[am][bn][r]);
      } else if (z == 1) {
        u16* dst = Kb + ((size_t)(b * 8 + h) * 1024 + l0) * 64 + d;
#pragma unroll
        for (int r = 0; r < 4; ++r) dst[(size_t)r * 64] = f2b(acc[am][bn][r]);
      } else {
        vshort4 vs;
#pragma unroll
        for (int r = 0; r < 4; ++r)
          vs[r] = (short)(mask[b * 1024 + l0 + r] ? f2b(acc[am][bn][r]) : (u16)0);
        *(vshort4*)(Vtb + ((size_t)(b * 8 + h) * 64 + d) * 1024 + l0) = vs;
      }
    }
  }
}

// ---- fused tanh-attention ---------------------------------------------------
__global__ __launch_bounds__(256) void attn_k(
    const u16* __restrict__ Qb, const u16* __restrict__ Kb,
    const u16* __restrict__ Vtb, const int* __restrict__ mask,
    float* __restrict__ AE, float* __restrict__ denom) {
  const int qt = blockIdx.x;
  const int bh = blockIdx.y;
  const int b = bh >> 3, h = bh & 7;
  __shared__ u16 Ks[64 * 64];     // [k][d] linear
  __shared__ u16 Vs[64 * 64];     // [d][k] linear (Vt tile)
  __shared__ u16 Es[4 * 16 * 64]; // per-wave E tile, xor-swizzled chunks
  __shared__ float mks[64];
  __shared__ float red[256];
  const int t = threadIdx.x, w = t >> 6, lane = t & 63;
  const int l15 = lane & 15, quad = lane >> 4;
  const u16* Kg = Kb + (size_t)bh * L_ * D_;
  const u16* Vg = Vtb + (size_t)bh * D_ * L_;
  // Q fragments live in registers for the whole kernel
  const u16* Qrow = Qb + ((size_t)bh * L_ + qt * 64 + w * 16 + l15) * 64;
  const bfrag bq0 = *(const bfrag*)(Qrow + quad * 8);
  const bfrag bq1 = *(const bfrag*)(Qrow + (quad + 4) * 8);
  const float mq = mask[b * L_ + qt * 64 + w * 16 + l15] ? 1.0f : 0.0f;

  const ffrag fz = {0.f, 0.f, 0.f, 0.f};
  ffrag acc[4] = {fz, fz, fz, fz};
  float dsum = 0.0f;

  for (int kt = 0; kt < 16; ++kt) {
    __syncthreads();
#pragma unroll
    for (int j = 0; j < 2; ++j) {
      const int c = w * 128 + j * 64 + lane;
      const int row = c >> 3, col = c & 7;
      gll16(Kg + ((size_t)(kt * 64 + row)) * 64 + col * 8,
            &Ks[(size_t)(w * 128 + j * 64) * 8]);
      gll16(Vg + (size_t)row * 1024 + kt * 64 + col * 8,
            &Vs[(size_t)(w * 128 + j * 64) * 8]);
    }
    if (t < 64) mks[t] = mask[b * L_ + kt * 64 + t] ? 1.0f : 0.0f;
    __syncthreads();

    // S^T = K·Q^T  (m=k-dim, n=q)
    ffrag st[4] = {fz, fz, fz, fz};
#pragma unroll
    for (int mb = 0; mb < 4; ++mb) {
      bfrag ak = *(const bfrag*)&Ks[(mb * 16 + l15) * 64 + quad * 8];
      st[mb] = __builtin_amdgcn_mfma_f32_16x16x32_bf16(ak, bq0, st[mb], 0, 0, 0);
    }
#pragma unroll
    for (int mb = 0; mb < 4; ++mb) {
      bfrag ak = *(const bfrag*)&Ks[(mb * 16 + l15) * 64 + (quad + 4) * 8];
      st[mb] = __builtin_amdgcn_mfma_f32_16x16x32_bf16(ak, bq1, st[mb], 0, 0, 0);
    }

    // E = exp(tanh(s/8)-1) = exp(-2/(e^(s/4)+1)); lane holds 4 consecutive k
#pragma unroll
    for (int mb = 0; mb < 4; ++mb) {
      float ee[4];
#pragma unroll
      for (int r = 0; r < 4; ++r) {
        const float xs = st[mb][r] * 0.25f;
        const float e = __expf(__fdividef(-2.0f, __expf(xs) + 1.0f));
        ee[r] = e;
        dsum += e * mks[mb * 16 + quad * 4 + r];
      }
      const unsigned p0 = pk2(ee[0], ee[1]);
      const unsigned p1 = pk2(ee[2], ee[3]);
      const int k0 = mb * 16 + quad * 4;
      u16* ep = &Es[w * 1024 + l15 * 64 + (((k0 >> 3) ^ (l15 & 7)) << 3) + (k0 & 7)];
      *(uint2*)ep = make_uint2(p0, p1);
    }

    // AE += E @ V   (A = Es rows (m=q), B = Vt rows (n=d)) — Es is wave-private
#pragma unroll
    for (int s = 0; s < 2; ++s) {
      bfrag ea = *(const bfrag*)&Es[w * 1024 + l15 * 64 + (((quad + 4 * s) ^ (l15 & 7)) << 3)];
#pragma unroll
      for (int nb = 0; nb < 4; ++nb) {
        bfrag bv = *(const bfrag*)&Vs[(nb * 16 + l15) * 64 + (quad + 4 * s) * 8];
        acc[nb] = __builtin_amdgcn_mfma_f32_16x16x32_bf16(ea, bv, acc[nb], 0, 0, 0);
      }
    }
  }

  const size_t aebase = ((size_t)b * L_ + qt * 64 + w * 16) * E_ + h * 64;
#pragma unroll
  for (int nb = 0; nb < 4; ++nb)
#pragma unroll
    for (int r = 0; r < 4; ++r)
      AE[aebase + (size_t)(quad * 4 + r) * E_ + nb * 16 + l15] = acc[nb][r];

  red[t] = dsum * mq;
  __syncthreads();
  for (int s2 = 128; s2 > 0; s2 >>= 1) { if (t < s2) red[t] += red[t + s2]; __syncthreads(); }
  if (t == 0) atomicAdd(denom + b, red[0]);
}

// ---- AG GEMM + combine epilogue: Cb = mq*(c1*AE + c2*(actb@Vt^T)) bf16 ------
__global__ __launch_bounds__(256) void gv_k(
    const u16* __restrict__ actb, const u16* __restrict__ Vtb,
    const float* __restrict__ AE, const int* __restrict__ mask,
    const float* __restrict__ sums, u16* __restrict__ Cb) {
  const int m0 = blockIdx.x * 128;     // q tile
  const int n0 = blockIdx.y * 64;      // e tile
  const int b = blockIdx.z;
  __shared__ u16 As[128 * 64];
  __shared__ u16 Bs[64 * 64];
  const int t = threadIdx.x, w = t >> 6, lane = t & 63;
  const int l15 = lane & 15, quad = lane >> 4;
  const float c1 = 0.5f / fmaxf(sums[b], TINYF);
  const float c2 = 0.5f / fmaxf(sums[8 + b], TINYF);
  const ffrag fz = {0.f, 0.f, 0.f, 0.f};
  ffrag acc[2][4];
#pragma unroll
  for (int am = 0; am < 2; ++am)
#pragma unroll
    for (int bn = 0; bn < 4; ++bn) acc[am][bn] = fz;

  for (int kk = 0; kk < 1024; kk += 64) {
    __syncthreads();
#pragma unroll
    for (int j = 0; j < 4; ++j) {
      const int c = w * 256 + j * 64 + lane;
      gll16(actb + (size_t)(m0 + (c >> 3)) * 1024 + kk + (c & 7) * 8,
            &As[(size_t)(w * 256 + j * 64) * 8]);
    }
#pragma unroll
    for (int j = 0; j < 2; ++j) {
      const int c = w * 128 + j * 64 + lane;
      gll16(Vtb + ((size_t)b * 512 + n0 + (c >> 3)) * 1024 + kk + (c & 7) * 8,
            &Bs[(size_t)(w * 128 + j * 64) * 8]);
    }
    __syncthreads();
#pragma unroll
    for (int s = 0; s < 2; ++s) {
      bfrag a0 = *(const bfrag*)&As[(w * 32 + l15) * 64 + (quad + 4 * s) * 8];
      bfrag a1 = *(const bfrag*)&As[(w * 32 + 16 + l15) * 64 + (quad + 4 * s) * 8];
#pragma unroll
      for (int bn = 0; bn < 4; ++bn) {
        bfrag bb = *(const bfrag*)&Bs[(bn * 16 + l15) * 64 + (quad + 4 * s) * 8];
        acc[0][bn] = __builtin_amdgcn_mfma_f32_16x16x32_bf16(a0, bb, acc[0][bn], 0, 0, 0);
        acc[1][bn] = __builtin_amdgcn_mfma_f32_16x16x32_bf16(a1, bb, acc[1][bn], 0, 0, 0);
      }
    }
  }
#pragma unroll
  for (int am = 0; am < 2; ++am) {
    const int qbase = m0 + w * 32 + am * 16 + quad * 4;
#pragma unroll
    for (int bn = 0; bn < 4; ++bn) {
      const int e = n0 + bn * 16 + l15;
#pragma unroll
      for (int r = 0; r < 4; ++r) {
        const int q = qbase + r;
        const size_t idx = ((size_t)b * 1024 + q) * 512 + e;
        const float v = mask[b * 1024 + q] ? (c1 * AE[idx] + c2 * acc[am][bn][r]) : 0.0f;
        Cb[idx] = f2b(v);
      }
    }
  }
}

// ---- out = Cb @ Wo^T (GLL GEMM) ---------------------------------------------
__global__ __launch_bounds__(256) void o_proj_k(
    const u16* __restrict__ Cb, const u16* __restrict__ Wb,
    float* __restrict__ out) {
  const int m0 = blockIdx.x * 128;
  const int n0 = blockIdx.y * 64;
  __shared__ u16 As[128 * 64];
  __shared__ u16 Bs[64 * 64];
  const int t = threadIdx.x, w = t >> 6, lane = t & 63;
  const int l15 = lane & 15, quad = lane >> 4;
  const ffrag fz = {0.f, 0.f, 0.f, 0.f};
  ffrag acc[2][4];
#pragma unroll
  for (int am = 0; am < 2; ++am)
#pragma unroll
    for (int bn = 0; bn < 4; ++bn) acc[am][bn] = fz;

  for (int kk = 0; kk < 512; kk += 64) {
    __syncthreads();
#pragma unroll
    for (int j = 0; j < 4; ++j) {
      const int c = w * 256 + j * 64 + lane;
      gll16(Cb + (size_t)(m0 + (c >> 3)) * 512 + kk + (c & 7) * 8,
            &As[(size_t)(w * 256 + j * 64) * 8]);
    }
#pragma unroll
    for (int j = 0; j < 2; ++j) {
      const int c = w * 128 + j * 64 + lane;
      gll16(Wb + (size_t)(1536 + n0 + (c >> 3)) * 512 + kk + (c & 7) * 8,
            &Bs[(size_t)(w * 128 + j * 64) * 8]);
    }
    __syncthreads();
#pragma unroll
    for (int s = 0; s < 2; ++s) {
      bfrag a0 = *(const bfrag*)&As[(w * 32 + l15) * 64 + (quad + 4 * s) * 8];
      bfrag a1 = *(const bfrag*)&As[(w * 32 + 16 + l15) * 64 + (quad + 4 * s) * 8];
#pragma unroll
      for (int bn = 0; bn < 4; ++bn) {
        bfrag bb = *(const bfrag*)&Bs[(bn * 16 + l15) * 64 + (quad + 4 * s) * 8];
        acc[0][bn] = __builtin_amdgcn_mfma_f32_16x16x32_bf16(a0, bb, acc[0][bn], 0, 0, 0);
        acc[1][bn] = __builtin_amdgcn_mfma_f32_16x16x32_bf16(a1, bb, acc[1][bn], 0, 0, 0);
      }
    }
  }
#pragma unroll
  for (int am = 0; am < 2; ++am) {
    const int mbase = m0 + w * 32 + am * 16 + quad * 4;
#pragma unroll
    for (int bn = 0; bn < 4; ++bn) {
      const int n = n0 + bn * 16 + l15;
#pragma unroll
      for (int r = 0; r < 4; ++r)
        out[(size_t)(mbase + r) * 512 + n] = acc[am][bn][r];
    }
  }
}

extern "C" void kernel_launch(void* const* d_in, const int* in_sizes, int n_in,
                              void* d_out, int out_size, void* d_ws, size_t ws_size,
                              hipStream_t stream) {
  const float* x  = (const float*)d_in[0];
  const int* mask = (const int*)d_in[1];
  const float* Wq = (const float*)d_in[2];
  const float* Wk = (const float*)d_in[3];
  const float* Wv = (const float*)d_in[4];
  const float* Wo = (const float*)d_in[5];
  const float* G  = (const float*)d_in[6];
  float* out = (float*)d_out;

  u16* xb   = (u16*)d_ws;                    // 8192*512
  u16* Wb   = xb + (size_t)8192 * 512;       // 2048*512
  u16* Qb   = Wb + (size_t)2048 * 512;       // QSZ
  u16* Kb   = Qb + QSZ;
  u16* Vtb  = Kb + QSZ;
  u16* actb = Vtb + QSZ;                     // 1024*1024
  u16* Cb   = actb + (size_t)1024 * 1024;    // 8192*512
  float* AE = (float*)(Cb + (size_t)8192 * 512);   // B*L*E
  float* R  = AE + (size_t)B_ * L_ * E_;     // 1024*8
  float* SUMS = R + 8192;                    // denom[8], gsums[8]

  prep_k<<<2560, 256, 0, stream>>>(x, Wq, Wk, Wv, Wo, xb, Wb, SUMS);
  softmax_g_k<<<1024, 256, 0, stream>>>(G, mask, actb, R);
  gsum_reduce_k<<<1, 256, 0, stream>>>(R, mask, SUMS);
  proj_k<<<dim3(64, 24), 256, 0, stream>>>(xb, Wb, mask, Qb, Kb, Vtb);
  attn_k<<<dim3(16, 64), 256, 0, stream>>>(Qb, Kb, Vtb, mask, AE, SUMS);
  gv_k<<<dim3(8, 8, 8), 256, 0, stream>>>(actb, Vtb, AE, mask, SUMS, Cb);
  o_proj_k<<<dim3(64, 8), 256, 0, stream>>>(Cb, Wb, out);
}

// Round 4
// 215.037 us; speedup vs baseline: 6.4466x; 1.0676x over previous
//
#include <hip/hip_runtime.h>
#include <math.h>

#define B_ 8
#define L_ 1024
#define E_ 512
#define H_ 8
#define D_ 64
#define QSZ (B_*H_*L_*D_)          // 4,194,304 elements
#define TINYF 1.175494350822287508e-38f

typedef unsigned short u16;
typedef __attribute__((ext_vector_type(8))) short bfrag;   // 8 bf16 (4 VGPRs)
typedef __attribute__((ext_vector_type(4))) float ffrag;   // 4 fp32 acc
typedef __attribute__((ext_vector_type(4))) short vshort4;

#if __has_builtin(__builtin_amdgcn_exp2f)
#define EXP2F(x) __builtin_amdgcn_exp2f(x)
#else
#define EXP2F(x) __expf((x) * 0.6931471805599453f)
#endif
#if __has_builtin(__builtin_amdgcn_rcpf)
#define RCPF(x) __builtin_amdgcn_rcpf(x)
#else
#define RCPF(x) (1.0f / (x))
#endif

__device__ __forceinline__ u16 f2b(float f) {
  unsigned u = __float_as_uint(f);
  u += 0x7fffu + ((u >> 16) & 1u);           // RNE
  return (u16)(u >> 16);
}
__device__ __forceinline__ unsigned pk2(float a, float b) {  // lo=rne(a), hi=rne(b)
  unsigned ua = __float_as_uint(a); ua += 0x7fffu + ((ua >> 16) & 1u);
  unsigned ub = __float_as_uint(b); ub += 0x7fffu + ((ub >> 16) & 1u);
  return (ua >> 16) | (ub & 0xffff0000u);
}
__device__ __forceinline__ float b2f(unsigned h) { return __uint_as_float(h << 16); }

__device__ __forceinline__ bfrag cvt8v(const float* __restrict__ src) {
  float4 a = *(const float4*)src;
  float4 b = *(const float4*)(src + 4);
  bfrag r;
  r[0]=(short)f2b(a.x); r[1]=(short)f2b(a.y); r[2]=(short)f2b(a.z); r[3]=(short)f2b(a.w);
  r[4]=(short)f2b(b.x); r[5]=(short)f2b(b.y); r[6]=(short)f2b(b.z); r[7]=(short)f2b(b.w);
  return r;
}

// async global->LDS, 16B per lane; lds base wave-uniform (HW adds lane*16)
__device__ __forceinline__ void gll16(const void* g, void* l) {
  __builtin_amdgcn_global_load_lds(
      (const __attribute__((address_space(1))) void*)g,
      (__attribute__((address_space(3))) void*)l, 16, 0, 0);
}

// ---- prep: fp32->bf16 conversions + zero sums -------------------------------
__global__ __launch_bounds__(256) void prep_k(
    const float* __restrict__ x, const float* __restrict__ Wq,
    const float* __restrict__ Wk, const float* __restrict__ Wv,
    const float* __restrict__ Wo, u16* __restrict__ xb, u16* __restrict__ Wb,
    float* __restrict__ sums) {
  const int bid = blockIdx.x, t = threadIdx.x;
  if (bid == 0 && t < 16) sums[t] = 0.0f;
  if (bid < 2048) {
    size_t c = (size_t)bid * 256 + t;
    *(bfrag*)&xb[c * 8] = cvt8v(x + c * 8);
  } else {
    const int c2 = bid - 2048;
    const float* src = (c2 < 128) ? Wq : (c2 < 256) ? Wk : (c2 < 384) ? Wv : Wo;
    const size_t base = (size_t)(c2 >> 7) * 262144;
    const size_t cc = (size_t)(c2 & 127) * 256 + t;
    *(bfrag*)&Wb[base + cc * 8] = cvt8v(src + cc * 8);
  }
}

// ---- softmax(G) rows -> actb bf16, plus masked row-dots R[q][b] -------------
__global__ __launch_bounds__(256) void softmax_g_k(
    const float* __restrict__ G, const int* __restrict__ mask,
    u16* __restrict__ actb, float* __restrict__ R) {
  const int q = blockIdx.x, t = threadIdx.x;
  const int w = t >> 6, lane = t & 63;
  __shared__ float sred[8];
  __shared__ float rred[4][8];
  float4 g4 = ((const float4*)(G + (size_t)q * 1024))[t];
  float m = fmaxf(fmaxf(g4.x, g4.y), fmaxf(g4.z, g4.w));
#pragma unroll
  for (int off = 32; off > 0; off >>= 1) m = fmaxf(m, __shfl_down(m, off));
  if (lane == 0) sred[w] = m;
  __syncthreads();
  m = fmaxf(fmaxf(sred[0], sred[1]), fmaxf(sred[2], sred[3]));
  float e0 = __expf(g4.x - m), e1 = __expf(g4.y - m);
  float e2 = __expf(g4.z - m), e3 = __expf(g4.w - m);
  float s = e0 + e1 + e2 + e3;
#pragma unroll
  for (int off = 32; off > 0; off >>= 1) s += __shfl_down(s, off);
  if (lane == 0) sred[4 + w] = s;
  __syncthreads();
  const float inv = 1.0f / (sred[4] + sred[5] + sred[6] + sred[7]);
  const unsigned p0 = pk2(e0 * inv, e1 * inv);
  const unsigned p1 = pk2(e2 * inv, e3 * inv);
  *(uint2*)&actb[(size_t)q * 1024 + t * 4] = make_uint2(p0, p1);
  const float r0 = b2f(p0 & 0xffffu), r1 = b2f(p0 >> 16);
  const float r2 = b2f(p1 & 0xffffu), r3 = b2f(p1 >> 16);
  float rd[8];
#pragma unroll
  for (int b = 0; b < 8; ++b) {
    const int* mkp = mask + b * 1024 + t * 4;
    rd[b] = (mkp[0] ? r0 : 0.f) + (mkp[1] ? r1 : 0.f) +
            (mkp[2] ? r2 : 0.f) + (mkp[3] ? r3 : 0.f);
#pragma unroll
    for (int off = 32; off > 0; off >>= 1) rd[b] += __shfl_down(rd[b], off);
  }
  if (lane == 0)
#pragma unroll
    for (int b = 0; b < 8; ++b) rred[w][b] = rd[b];
  __syncthreads();
  if (t < 8) R[q * 8 + t] = rred[0][t] + rred[1][t] + rred[2][t] + rred[3][t];
}

__global__ __launch_bounds__(256) void gsum_reduce_k(
    const float* __restrict__ R, const int* __restrict__ mask,
    float* __restrict__ sums) {
  const int t = threadIdx.x, w = t >> 6, lane = t & 63;
  __shared__ float rr[4][8];
  float acc[8] = {0,0,0,0,0,0,0,0};
  for (int q = t; q < 1024; q += 256)
#pragma unroll
    for (int b = 0; b < 8; ++b)
      if (mask[b * 1024 + q]) acc[b] += R[q * 8 + b];
#pragma unroll
  for (int b = 0; b < 8; ++b) {
#pragma unroll
    for (int off = 32; off > 0; off >>= 1) acc[b] += __shfl_down(acc[b], off);
  }
  if (lane == 0)
#pragma unroll
    for (int b = 0; b < 8; ++b) rr[w][b] = acc[b];
  __syncthreads();
  if (t < 8) sums[8 + t] = rr[0][t] + rr[1][t] + rr[2][t] + rr[3][t];
}

// ---- QKV projection: GLL GEMM 128x64 (swizzled), xb @ Wb[0:1536]^T ----------
__global__ __launch_bounds__(256) void proj_k(
    const u16* __restrict__ xb, const u16* __restrict__ Wb,
    const int* __restrict__ mask,
    u16* __restrict__ Qb, u16* __restrict__ Kb, u16* __restrict__ Vtb) {
  const int m0 = blockIdx.x * 128;
  const int n0 = blockIdx.y * 64;
  __shared__ u16 As[128 * 64];
  __shared__ u16 Bs[64 * 64];
  const int t = threadIdx.x, w = t >> 6, lane = t & 63;
  const int l15 = lane & 15, quad = lane >> 4;
  const int x7 = l15 & 7;
  const ffrag fz = {0.f, 0.f, 0.f, 0.f};
  ffrag acc[2][4];
#pragma unroll
  for (int am = 0; am < 2; ++am)
#pragma unroll
    for (int bn = 0; bn < 4; ++bn) acc[am][bn] = fz;

  for (int kk = 0; kk < 512; kk += 64) {
    __syncthreads();
#pragma unroll
    for (int j = 0; j < 4; ++j) {
      const int c = w * 256 + j * 64 + lane;
      const int row = c >> 3, ck = (c & 7) ^ (row & 7);
      gll16(xb + (size_t)(m0 + row) * 512 + kk + ck * 8,
            &As[(size_t)(w * 256 + j * 64) * 8]);
    }
#pragma unroll
    for (int j = 0; j < 2; ++j) {
      const int c = w * 128 + j * 64 + lane;
      const int row = c >> 3, ck = (c & 7) ^ (row & 7);
      gll16(Wb + (size_t)(n0 + row) * 512 + kk + ck * 8,
            &Bs[(size_t)(w * 128 + j * 64) * 8]);
    }
    __syncthreads();
#pragma unroll
    for (int s = 0; s < 2; ++s) {
      const int co = ((quad + 4 * s) ^ x7) << 3;
      bfrag a0 = *(const bfrag*)&As[(w * 32 + l15) * 64 + co];
      bfrag a1 = *(const bfrag*)&As[(w * 32 + 16 + l15) * 64 + co];
#pragma unroll
      for (int bn = 0; bn < 4; ++bn) {
        bfrag bb = *(const bfrag*)&Bs[(bn * 16 + l15) * 64 + co];
        acc[0][bn] = __builtin_amdgcn_mfma_f32_16x16x32_bf16(a0, bb, acc[0][bn], 0, 0, 0);
        acc[1][bn] = __builtin_amdgcn_mfma_f32_16x16x32_bf16(a1, bb, acc[1][bn], 0, 0, 0);
      }
    }
  }
  const int z = n0 >> 9;
  const int c0 = n0 & 511;
#pragma unroll
  for (int am = 0; am < 2; ++am) {
    const int mbase = m0 + w * 32 + am * 16 + quad * 4;
    const int b = mbase >> 10, l0 = mbase & 1023;
#pragma unroll
    for (int bn = 0; bn < 4; ++bn) {
      const int nc = c0 + bn * 16 + l15;
      const int h = nc >> 6, d = nc & 63;
      if (z == 0) {
        u16* dst = Qb + ((size_t)(b * 8 + h) * 1024 + l0) * 64 + d;
#pragma unroll
        for (int r = 0; r < 4; ++r) dst[(size_t)r * 64] = f2b(acc[am][bn][r]);
      } else if (z == 1) {
        u16* dst = Kb + ((size_t)(b * 8 + h) * 1024 + l0) * 64 + d;
#pragma unroll
        for (int r = 0; r < 4; ++r) dst[(size_t)r * 64] = f2b(acc[am][bn][r]);
      } else {
        vshort4 vs;
#pragma unroll
        for (int r = 0; r < 4; ++r)
          vs[r] = (short)(mask[b * 1024 + l0 + r] ? f2b(acc[am][bn][r]) : (u16)0);
        *(vshort4*)(Vtb + ((size_t)(b * 8 + h) * 64 + d) * 1024 + l0) = vs;
      }
    }
  }
}

// ---- fused tanh-attention: dbuf GLL, swizzled frags, MFMA denominator -------
__global__ __launch_bounds__(256) void attn_k(
    const u16* __restrict__ Qb, const u16* __restrict__ Kb,
    const u16* __restrict__ Vtb, const int* __restrict__ mask,
    float* __restrict__ AE, float* __restrict__ denom) {
  const int qt = blockIdx.x;
  const int bh = blockIdx.y;
  const int b = bh >> 3, h = bh & 7;
  __shared__ u16 Ks[2][64 * 64];              // [k][d], swizzled chunks
  __shared__ u16 Vs[2][64 * 64];              // [d][k], swizzled chunks
  __shared__ __align__(16) u16 Es[4 * 16 * 64]; // per-wave E tile (reused as red)
  const int t = threadIdx.x, w = t >> 6, lane = t & 63;
  const int l15 = lane & 15, quad = lane >> 4;
  const int x7 = l15 & 7;
  const u16* Kg = Kb + (size_t)bh * L_ * D_;
  const u16* Vg = Vtb + (size_t)bh * D_ * L_;
  const u16* Qrow = Qb + ((size_t)bh * L_ + qt * 64 + w * 16 + l15) * 64;
  const bfrag bq0 = *(const bfrag*)(Qrow + quad * 8);
  const bfrag bq1 = *(const bfrag*)(Qrow + (quad + 4) * 8);

  const ffrag fz = {0.f, 0.f, 0.f, 0.f};
  ffrag acc[4] = {fz, fz, fz, fz};
  ffrag dacc = fz;

  // stage tile kt into buffer p (global-side swizzle)
  auto stage = [&](int p, int kt) {
#pragma unroll
    for (int j = 0; j < 2; ++j) {
      const int c = w * 128 + j * 64 + lane;
      const int row = c >> 3, ck = (c & 7) ^ (row & 7);
      gll16(Kg + (size_t)(kt * 64 + row) * 64 + ck * 8,
            &Ks[p][(size_t)(w * 128 + j * 64) * 8]);
      gll16(Vg + (size_t)row * 1024 + kt * 64 + ck * 8,
            &Vs[p][(size_t)(w * 128 + j * 64) * 8]);
    }
  };

  stage(0, 0);
  __syncthreads();

  for (int kt = 0; kt < 16; ++kt) {
    const int p = kt & 1;
    if (kt < 15) stage(1 - p, kt + 1);   // prefetch overlaps compute

    // S^T = K·Q^T  (m=k-dim, n=q)
    ffrag st[4] = {fz, fz, fz, fz};
#pragma unroll
    for (int s = 0; s < 2; ++s) {
      const int co = ((quad + 4 * s) ^ x7) << 3;
      const bfrag bq = s ? bq1 : bq0;
#pragma unroll
      for (int mb = 0; mb < 4; ++mb) {
        bfrag ak = *(const bfrag*)&Ks[p][(mb * 16 + l15) * 64 + co];
        st[mb] = __builtin_amdgcn_mfma_f32_16x16x32_bf16(ak, bq, st[mb], 0, 0, 0);
      }
    }

    // E = exp(tanh(s/8)-1) = exp2(-2*log2e / (exp2(s*log2e/4) + 1))
#pragma unroll
    for (int mb = 0; mb < 4; ++mb) {
      float ee[4];
#pragma unroll
      for (int r = 0; r < 4; ++r) {
        const float tt = EXP2F(st[mb][r] * 0.360673760222f);
        ee[r] = EXP2F(RCPF(tt + 1.0f) * -2.88539008178f);
      }
      const int k0 = mb * 16 + quad * 4;
      u16* ep = &Es[w * 1024 + l15 * 64 + (((k0 >> 3) ^ x7) << 3) + (k0 & 7)];
      *(uint2*)ep = make_uint2(pk2(ee[0], ee[1]), pk2(ee[2], ee[3]));
    }

    // mask B-frags for the denominator MFMA (broadcast int4 loads, L1-hit)
    const int* mrow = mask + b * L_ + kt * 64 + quad * 8;
    int4 mi0 = *(const int4*)(mrow);
    int4 mi1 = *(const int4*)(mrow + 4);
    int4 mi2 = *(const int4*)(mrow + 32);
    int4 mi3 = *(const int4*)(mrow + 36);
    bfrag bm0, bm1;
    bm0[0] = mi0.x ? (short)0x3F80 : (short)0; bm0[1] = mi0.y ? (short)0x3F80 : (short)0;
    bm0[2] = mi0.z ? (short)0x3F80 : (short)0; bm0[3] = mi0.w ? (short)0x3F80 : (short)0;
    bm0[4] = mi1.x ? (short)0x3F80 : (short)0; bm0[5] = mi1.y ? (short)0x3F80 : (short)0;
    bm0[6] = mi1.z ? (short)0x3F80 : (short)0; bm0[7] = mi1.w ? (short)0x3F80 : (short)0;
    bm1[0] = mi2.x ? (short)0x3F80 : (short)0; bm1[1] = mi2.y ? (short)0x3F80 : (short)0;
    bm1[2] = mi2.z ? (short)0x3F80 : (short)0; bm1[3] = mi2.w ? (short)0x3F80 : (short)0;
    bm1[4] = mi3.x ? (short)0x3F80 : (short)0; bm1[5] = mi3.y ? (short)0x3F80 : (short)0;
    bm1[6] = mi3.z ? (short)0x3F80 : (short)0; bm1[7] = mi3.w ? (short)0x3F80 : (short)0;

    // Es A-frags (wave-private; compiler handles lgkmcnt)
    bfrag ea0 = *(const bfrag*)&Es[w * 1024 + l15 * 64 + ((quad ^ x7) << 3)];
    bfrag ea1 = *(const bfrag*)&Es[w * 1024 + l15 * 64 + (((quad + 4) ^ x7) << 3)];

    // denominator: dacc[q][*] += E·mk
    dacc = __builtin_amdgcn_mfma_f32_16x16x32_bf16(ea0, bm0, dacc, 0, 0, 0);
    dacc = __builtin_amdgcn_mfma_f32_16x16x32_bf16(ea1, bm1, dacc, 0, 0, 0);

    // AE += E @ V
#pragma unroll
    for (int s = 0; s < 2; ++s) {
      const int co = ((quad + 4 * s) ^ x7) << 3;
      const bfrag ea = s ? ea1 : ea0;
#pragma unroll
      for (int nb = 0; nb < 4; ++nb) {
        bfrag bv = *(const bfrag*)&Vs[p][(nb * 16 + l15) * 64 + co];
        acc[nb] = __builtin_amdgcn_mfma_f32_16x16x32_bf16(ea, bv, acc[nb], 0, 0, 0);
      }
    }
    __syncthreads();   // buf[p] reads done; prefetch into buf[1-p] drained
  }

  const size_t aebase = ((size_t)b * L_ + qt * 64 + w * 16) * E_ + h * 64;
#pragma unroll
  for (int nb = 0; nb < 4; ++nb)
#pragma unroll
    for (int r = 0; r < 4; ++r)
      AE[aebase + (size_t)(quad * 4 + r) * E_ + nb * 16 + l15] = acc[nb][r];

  // block-reduce masked denominator (dacc columns identical; use l15==0)
  float val = 0.f;
  if (l15 == 0) {
    const int qb = b * L_ + qt * 64 + w * 16 + quad * 4;
#pragma unroll
    for (int r = 0; r < 4; ++r) val += mask[qb + r] ? dacc[r] : 0.f;
  }
  float* red = (float*)Es;
  red[t] = val;
  __syncthreads();
  for (int s2 = 128; s2 > 0; s2 >>= 1) { if (t < s2) red[t] += red[t + s2]; __syncthreads(); }
  if (t == 0) atomicAdd(denom + b, red[0]);
}

// ---- AG GEMM + combine epilogue: Cb = mq*(c1*AE + c2*(actb@Vt^T)) bf16 ------
__global__ __launch_bounds__(256) void gv_k(
    const u16* __restrict__ actb, const u16* __restrict__ Vtb,
    const float* __restrict__ AE, const int* __restrict__ mask,
    const float* __restrict__ sums, u16* __restrict__ Cb) {
  const int m0 = blockIdx.x * 128;
  const int n0 = blockIdx.y * 64;
  const int b = blockIdx.z;
  __shared__ u16 As[128 * 64];
  __shared__ u16 Bs[64 * 64];
  const int t = threadIdx.x, w = t >> 6, lane = t & 63;
  const int l15 = lane & 15, quad = lane >> 4;
  const int x7 = l15 & 7;
  const float c1 = 0.5f / fmaxf(sums[b], TINYF);
  const float c2 = 0.5f / fmaxf(sums[8 + b], TINYF);
  const ffrag fz = {0.f, 0.f, 0.f, 0.f};
  ffrag acc[2][4];
#pragma unroll
  for (int am = 0; am < 2; ++am)
#pragma unroll
    for (int bn = 0; bn < 4; ++bn) acc[am][bn] = fz;

  for (int kk = 0; kk < 1024; kk += 64) {
    __syncthreads();
#pragma unroll
    for (int j = 0; j < 4; ++j) {
      const int c = w * 256 + j * 64 + lane;
      const int row = c >> 3, ck = (c & 7) ^ (row & 7);
      gll16(actb + (size_t)(m0 + row) * 1024 + kk + ck * 8,
            &As[(size_t)(w * 256 + j * 64) * 8]);
    }
#pragma unroll
    for (int j = 0; j < 2; ++j) {
      const int c = w * 128 + j * 64 + lane;
      const int row = c >> 3, ck = (c & 7) ^ (row & 7);
      gll16(Vtb + ((size_t)b * 512 + n0 + row) * 1024 + kk + ck * 8,
            &Bs[(size_t)(w * 128 + j * 64) * 8]);
    }
    __syncthreads();
#pragma unroll
    for (int s = 0; s < 2; ++s) {
      const int co = ((quad + 4 * s) ^ x7) << 3;
      bfrag a0 = *(const bfrag*)&As[(w * 32 + l15) * 64 + co];
      bfrag a1 = *(const bfrag*)&As[(w * 32 + 16 + l15) * 64 + co];
#pragma unroll
      for (int bn = 0; bn < 4; ++bn) {
        bfrag bb = *(const bfrag*)&Bs[(bn * 16 + l15) * 64 + co];
        acc[0][bn] = __builtin_amdgcn_mfma_f32_16x16x32_bf16(a0, bb, acc[0][bn], 0, 0, 0);
        acc[1][bn] = __builtin_amdgcn_mfma_f32_16x16x32_bf16(a1, bb, acc[1][bn], 0, 0, 0);
      }
    }
  }
#pragma unroll
  for (int am = 0; am < 2; ++am) {
    const int qbase = m0 + w * 32 + am * 16 + quad * 4;
#pragma unroll
    for (int bn = 0; bn < 4; ++bn) {
      const int e = n0 + bn * 16 + l15;
#pragma unroll
      for (int r = 0; r < 4; ++r) {
        const int q = qbase + r;
        const size_t idx = ((size_t)b * 1024 + q) * 512 + e;
        const float v = mask[b * 1024 + q] ? (c1 * AE[idx] + c2 * acc[am][bn][r]) : 0.0f;
        Cb[idx] = f2b(v);
      }
    }
  }
}

// ---- out = Cb @ Wo^T (GLL GEMM, swizzled) -----------------------------------
__global__ __launch_bounds__(256) void o_proj_k(
    const u16* __restrict__ Cb, const u16* __restrict__ Wb,
    float* __restrict__ out) {
  const int m0 = blockIdx.x * 128;
  const int n0 = blockIdx.y * 64;
  __shared__ u16 As[128 * 64];
  __shared__ u16 Bs[64 * 64];
  const int t = threadIdx.x, w = t >> 6, lane = t & 63;
  const int l15 = lane & 15, quad = lane >> 4;
  const int x7 = l15 & 7;
  const ffrag fz = {0.f, 0.f, 0.f, 0.f};
  ffrag acc[2][4];
#pragma unroll
  for (int am = 0; am < 2; ++am)
#pragma unroll
    for (int bn = 0; bn < 4; ++bn) acc[am][bn] = fz;

  for (int kk = 0; kk < 512; kk += 64) {
    __syncthreads();
#pragma unroll
    for (int j = 0; j < 4; ++j) {
      const int c = w * 256 + j * 64 + lane;
      const int row = c >> 3, ck = (c & 7) ^ (row & 7);
      gll16(Cb + (size_t)(m0 + row) * 512 + kk + ck * 8,
            &As[(size_t)(w * 256 + j * 64) * 8]);
    }
#pragma unroll
    for (int j = 0; j < 2; ++j) {
      const int c = w * 128 + j * 64 + lane;
      const int row = c >> 3, ck = (c & 7) ^ (row & 7);
      gll16(Wb + (size_t)(1536 + n0 + row) * 512 + kk + ck * 8,
            &Bs[(size_t)(w * 128 + j * 64) * 8]);
    }
    __syncthreads();
#pragma unroll
    for (int s = 0; s < 2; ++s) {
      const int co = ((quad + 4 * s) ^ x7) << 3;
      bfrag a0 = *(const bfrag*)&As[(w * 32 + l15) * 64 + co];
      bfrag a1 = *(const bfrag*)&As[(w * 32 + 16 + l15) * 64 + co];
#pragma unroll
      for (int bn = 0; bn < 4; ++bn) {
        bfrag bb = *(const bfrag*)&Bs[(bn * 16 + l15) * 64 + co];
        acc[0][bn] = __builtin_amdgcn_mfma_f32_16x16x32_bf16(a0, bb, acc[0][bn], 0, 0, 0);
        acc[1][bn] = __builtin_amdgcn_mfma_f32_16x16x32_bf16(a1, bb, acc[1][bn], 0, 0, 0);
      }
    }
  }
#pragma unroll
  for (int am = 0; am < 2; ++am) {
    const int mbase = m0 + w * 32 + am * 16 + quad * 4;
#pragma unroll
    for (int bn = 0; bn < 4; ++bn) {
      const int n = n0 + bn * 16 + l15;
#pragma unroll
      for (int r = 0; r < 4; ++r)
        out[(size_t)(mbase + r) * 512 + n] = acc[am][bn][r];
    }
  }
}

extern "C" void kernel_launch(void* const* d_in, const int* in_sizes, int n_in,
                              void* d_out, int out_size, void* d_ws, size_t ws_size,
                              hipStream_t stream) {
  const float* x  = (const float*)d_in[0];
  const int* mask = (const int*)d_in[1];
  const float* Wq = (const float*)d_in[2];
  const float* Wk = (const float*)d_in[3];
  const float* Wv = (const float*)d_in[4];
  const float* Wo = (const float*)d_in[5];
  const float* G  = (const float*)d_in[6];
  float* out = (float*)d_out;

  u16* xb   = (u16*)d_ws;                    // 8192*512
  u16* Wb   = xb + (size_t)8192 * 512;       // 2048*512
  u16* Qb   = Wb + (size_t)2048 * 512;       // QSZ
  u16* Kb   = Qb + QSZ;
  u16* Vtb  = Kb + QSZ;
  u16* actb = Vtb + QSZ;                     // 1024*1024
  u16* Cb   = actb + (size_t)1024 * 1024;    // 8192*512
  float* AE = (float*)(Cb + (size_t)8192 * 512);   // B*L*E
  float* R  = AE + (size_t)B_ * L_ * E_;     // 1024*8
  float* SUMS = R + 8192;                    // denom[8], gsums[8]

  prep_k<<<2560, 256, 0, stream>>>(x, Wq, Wk, Wv, Wo, xb, Wb, SUMS);
  softmax_g_k<<<1024, 256, 0, stream>>>(G, mask, actb, R);
  gsum_reduce_k<<<1, 256, 0, stream>>>(R, mask, SUMS);
  proj_k<<<dim3(64, 24), 256, 0, stream>>>(xb, Wb, mask, Qb, Kb, Vtb);
  attn_k<<<dim3(16, 64), 256, 0, stream>>>(Qb, Kb, Vtb, mask, AE, SUMS);
  gv_k<<<dim3(8, 8, 8), 256, 0, stream>>>(actb, Vtb, AE, mask, SUMS, Cb);
  o_proj_k<<<dim3(64, 8), 256, 0, stream>>>(Cb, Wb, out);
}

// Round 5
// 196.836 us; speedup vs baseline: 7.0427x; 1.0925x over previous
//
#include <hip/hip_runtime.h>
#include <math.h>

#define B_ 8
#define L_ 1024
#define E_ 512
#define H_ 8
#define D_ 64
#define QSZ (B_*H_*L_*D_)          // 4,194,304 elements
#define TINYF 1.175494350822287508e-38f

typedef unsigned short u16;
typedef __attribute__((ext_vector_type(8))) short bfrag;    // 8 bf16 (4 VGPRs)
typedef __attribute__((ext_vector_type(4))) float ffrag;    // 4 fp32 acc (16x16)
typedef __attribute__((ext_vector_type(16))) float ffrag16; // 16 fp32 acc (32x32)
typedef __attribute__((ext_vector_type(4))) short vshort4;

#if __has_builtin(__builtin_amdgcn_exp2f)
#define EXP2F(x) __builtin_amdgcn_exp2f(x)
#else
#define EXP2F(x) __expf((x) * 0.6931471805599453f)
#endif
#if __has_builtin(__builtin_amdgcn_rcpf)
#define RCPF(x) __builtin_amdgcn_rcpf(x)
#else
#define RCPF(x) (1.0f / (x))
#endif

__device__ __forceinline__ u16 f2b(float f) {
  unsigned u = __float_as_uint(f);
  u += 0x7fffu + ((u >> 16) & 1u);           // RNE
  return (u16)(u >> 16);
}
__device__ __forceinline__ unsigned pk2(float a, float b) {  // lo=rne(a), hi=rne(b)
  unsigned ua = __float_as_uint(a); ua += 0x7fffu + ((ua >> 16) & 1u);
  unsigned ub = __float_as_uint(b); ub += 0x7fffu + ((ub >> 16) & 1u);
  return (ua >> 16) | (ub & 0xffff0000u);
}
__device__ __forceinline__ float b2f(unsigned h) { return __uint_as_float(h << 16); }
__device__ __forceinline__ float blo(unsigned u) { return __uint_as_float(u << 16); }
__device__ __forceinline__ float bhi(unsigned u) { return __uint_as_float(u & 0xffff0000u); }

__device__ __forceinline__ bfrag cvt8v(const float* __restrict__ src) {
  float4 a = *(const float4*)src;
  float4 b = *(const float4*)(src + 4);
  bfrag r;
  r[0]=(short)f2b(a.x); r[1]=(short)f2b(a.y); r[2]=(short)f2b(a.z); r[3]=(short)f2b(a.w);
  r[4]=(short)f2b(b.x); r[5]=(short)f2b(b.y); r[6]=(short)f2b(b.z); r[7]=(short)f2b(b.w);
  return r;
}

// async global->LDS, 16B per lane; lds base wave-uniform (HW adds lane*16)
__device__ __forceinline__ void gll16(const void* g, void* l) {
  __builtin_amdgcn_global_load_lds(
      (const __attribute__((address_space(1))) void*)g,
      (__attribute__((address_space(3))) void*)l, 16, 0, 0);
}

// ---- prep: fp32->bf16 conversions + zero sums -------------------------------
__global__ __launch_bounds__(256) void prep_k(
    const float* __restrict__ x, const float* __restrict__ Wq,
    const float* __restrict__ Wk, const float* __restrict__ Wv,
    const float* __restrict__ Wo, u16* __restrict__ xb, u16* __restrict__ Wb,
    float* __restrict__ sums) {
  const int bid = blockIdx.x, t = threadIdx.x;
  if (bid == 0 && t < 16) sums[t] = 0.0f;
  if (bid < 2048) {
    size_t c = (size_t)bid * 256 + t;
    *(bfrag*)&xb[c * 8] = cvt8v(x + c * 8);
  } else {
    const int c2 = bid - 2048;
    const float* src = (c2 < 128) ? Wq : (c2 < 256) ? Wk : (c2 < 384) ? Wv : Wo;
    const size_t base = (size_t)(c2 >> 7) * 262144;
    const size_t cc = (size_t)(c2 & 127) * 256 + t;
    *(bfrag*)&Wb[base + cc * 8] = cvt8v(src + cc * 8);
  }
}

// ---- softmax(G) rows -> actb bf16, plus masked row-dots R[q][b] -------------
__global__ __launch_bounds__(256) void softmax_g_k(
    const float* __restrict__ G, const int* __restrict__ mask,
    u16* __restrict__ actb, float* __restrict__ R) {
  const int q = blockIdx.x, t = threadIdx.x;
  const int w = t >> 6, lane = t & 63;
  __shared__ float sred[8];
  __shared__ float rred[4][8];
  float4 g4 = ((const float4*)(G + (size_t)q * 1024))[t];
  float m = fmaxf(fmaxf(g4.x, g4.y), fmaxf(g4.z, g4.w));
#pragma unroll
  for (int off = 32; off > 0; off >>= 1) m = fmaxf(m, __shfl_down(m, off));
  if (lane == 0) sred[w] = m;
  __syncthreads();
  m = fmaxf(fmaxf(sred[0], sred[1]), fmaxf(sred[2], sred[3]));
  float e0 = __expf(g4.x - m), e1 = __expf(g4.y - m);
  float e2 = __expf(g4.z - m), e3 = __expf(g4.w - m);
  float s = e0 + e1 + e2 + e3;
#pragma unroll
  for (int off = 32; off > 0; off >>= 1) s += __shfl_down(s, off);
  if (lane == 0) sred[4 + w] = s;
  __syncthreads();
  const float inv = 1.0f / (sred[4] + sred[5] + sred[6] + sred[7]);
  const unsigned p0 = pk2(e0 * inv, e1 * inv);
  const unsigned p1 = pk2(e2 * inv, e3 * inv);
  *(uint2*)&actb[(size_t)q * 1024 + t * 4] = make_uint2(p0, p1);
  const float r0 = blo(p0), r1 = bhi(p0);
  const float r2 = blo(p1), r3 = bhi(p1);
  float rd[8];
#pragma unroll
  for (int b = 0; b < 8; ++b) {
    const int* mkp = mask + b * 1024 + t * 4;
    rd[b] = (mkp[0] ? r0 : 0.f) + (mkp[1] ? r1 : 0.f) +
            (mkp[2] ? r2 : 0.f) + (mkp[3] ? r3 : 0.f);
#pragma unroll
    for (int off = 32; off > 0; off >>= 1) rd[b] += __shfl_down(rd[b], off);
  }
  if (lane == 0)
#pragma unroll
    for (int b = 0; b < 8; ++b) rred[w][b] = rd[b];
  __syncthreads();
  if (t < 8) R[q * 8 + t] = rred[0][t] + rred[1][t] + rred[2][t] + rred[3][t];
}

__global__ __launch_bounds__(256) void gsum_reduce_k(
    const float* __restrict__ R, const int* __restrict__ mask,
    float* __restrict__ sums) {
  const int t = threadIdx.x, w = t >> 6, lane = t & 63;
  __shared__ float rr[4][8];
  float acc[8] = {0,0,0,0,0,0,0,0};
  for (int q = t; q < 1024; q += 256)
#pragma unroll
    for (int b = 0; b < 8; ++b)
      if (mask[b * 1024 + q]) acc[b] += R[q * 8 + b];
#pragma unroll
  for (int b = 0; b < 8; ++b) {
#pragma unroll
    for (int off = 32; off > 0; off >>= 1) acc[b] += __shfl_down(acc[b], off);
  }
  if (lane == 0)
#pragma unroll
    for (int b = 0; b < 8; ++b) rr[w][b] = acc[b];
  __syncthreads();
  if (t < 8) sums[8 + t] = rr[0][t] + rr[1][t] + rr[2][t] + rr[3][t];
}

// ---- QKV projection: GLL GEMM 128x64 (swizzled), xb @ Wb[0:1536]^T ----------
__global__ __launch_bounds__(256) void proj_k(
    const u16* __restrict__ xb, const u16* __restrict__ Wb,
    const int* __restrict__ mask,
    u16* __restrict__ Qb, u16* __restrict__ Kb, u16* __restrict__ Vtb) {
  const int m0 = blockIdx.x * 128;
  const int n0 = blockIdx.y * 64;
  __shared__ u16 As[128 * 64];
  __shared__ u16 Bs[64 * 64];
  const int t = threadIdx.x, w = t >> 6, lane = t & 63;
  const int l15 = lane & 15, quad = lane >> 4;
  const int x7 = l15 & 7;
  const ffrag fz = {0.f, 0.f, 0.f, 0.f};
  ffrag acc[2][4];
#pragma unroll
  for (int am = 0; am < 2; ++am)
#pragma unroll
    for (int bn = 0; bn < 4; ++bn) acc[am][bn] = fz;

  for (int kk = 0; kk < 512; kk += 64) {
    __syncthreads();
#pragma unroll
    for (int j = 0; j < 4; ++j) {
      const int c = w * 256 + j * 64 + lane;
      const int row = c >> 3, ck = (c & 7) ^ (row & 7);
      gll16(xb + (size_t)(m0 + row) * 512 + kk + ck * 8,
            &As[(size_t)(w * 256 + j * 64) * 8]);
    }
#pragma unroll
    for (int j = 0; j < 2; ++j) {
      const int c = w * 128 + j * 64 + lane;
      const int row = c >> 3, ck = (c & 7) ^ (row & 7);
      gll16(Wb + (size_t)(n0 + row) * 512 + kk + ck * 8,
            &Bs[(size_t)(w * 128 + j * 64) * 8]);
    }
    __syncthreads();
#pragma unroll
    for (int s = 0; s < 2; ++s) {
      const int co = ((quad + 4 * s) ^ x7) << 3;
      bfrag a0 = *(const bfrag*)&As[(w * 32 + l15) * 64 + co];
      bfrag a1 = *(const bfrag*)&As[(w * 32 + 16 + l15) * 64 + co];
#pragma unroll
      for (int bn = 0; bn < 4; ++bn) {
        bfrag bb = *(const bfrag*)&Bs[(bn * 16 + l15) * 64 + co];
        acc[0][bn] = __builtin_amdgcn_mfma_f32_16x16x32_bf16(a0, bb, acc[0][bn], 0, 0, 0);
        acc[1][bn] = __builtin_amdgcn_mfma_f32_16x16x32_bf16(a1, bb, acc[1][bn], 0, 0, 0);
      }
    }
  }
  const int z = n0 >> 9;
  const int c0 = n0 & 511;
#pragma unroll
  for (int am = 0; am < 2; ++am) {
    const int mbase = m0 + w * 32 + am * 16 + quad * 4;
    const int b = mbase >> 10, l0 = mbase & 1023;
#pragma unroll
    for (int bn = 0; bn < 4; ++bn) {
      const int nc = c0 + bn * 16 + l15;
      const int h = nc >> 6, d = nc & 63;
      if (z == 0) {
        u16* dst = Qb + ((size_t)(b * 8 + h) * 1024 + l0) * 64 + d;
#pragma unroll
        for (int r = 0; r < 4; ++r) dst[(size_t)r * 64] = f2b(acc[am][bn][r]);
      } else if (z == 1) {
        u16* dst = Kb + ((size_t)(b * 8 + h) * 1024 + l0) * 64 + d;
#pragma unroll
        for (int r = 0; r < 4; ++r) dst[(size_t)r * 64] = f2b(acc[am][bn][r]);
      } else {
        vshort4 vs;
#pragma unroll
        for (int r = 0; r < 4; ++r)
          vs[r] = (short)(mask[b * 1024 + l0 + r] ? f2b(acc[am][bn][r]) : (u16)0);
        *(vshort4*)(Vtb + ((size_t)(b * 8 + h) * 64 + d) * 1024 + l0) = vs;
      }
    }
  }
}

// ---- fused tanh-attention + global-mix GEMM, 32x32 MFMA ---------------------
// Per (qt, bh): S^T=K·Q^T; E=exp(tanh(s/8)-1); AE=E@V; AG=act@V (shares V
// B-frags); denom via MFMA with broadcast mask B-frags. AE/AG stored bf16.
__global__ __launch_bounds__(256) void attn_k(
    const u16* __restrict__ Qb, const u16* __restrict__ Kb,
    const u16* __restrict__ Vtb, const u16* __restrict__ actb,
    const int* __restrict__ mask,
    u16* __restrict__ AEb, u16* __restrict__ AGb, float* __restrict__ denom) {
  const int qt = blockIdx.x;
  const int bh = blockIdx.y;
  const int b = bh >> 3, h = bh & 7;
  __shared__ __align__(16) u16 Ks[64 * 64];    // [k][d], chunk-swizzled
  __shared__ __align__(16) u16 Vs[64 * 64];    // [d][k], chunk-swizzled
  __shared__ __align__(16) u16 Acts[64 * 64];  // [q][k], chunk-swizzled
  __shared__ __align__(16) u16 Es[64 * 64];    // [q][k], chunk-swizzled
  __shared__ __align__(16) u16 Ms[16 * 64];    // [kt][k] bf16 mask
  const int t = threadIdx.x, w = t >> 6, lane = t & 63;
  const int l31 = lane & 31, hi = lane >> 5;
  const int qsb = w >> 1, msb = w & 1;   // S-phase: q-block, k(m)-block
  const int qpb = w & 1, dpb = w >> 1;   // PV-phase: q-block, d-block

  const u16* Kg = Kb + (size_t)bh * 65536;
  const u16* Vg = Vtb + (size_t)bh * 65536;
  const u16* Ag = actb + (size_t)(qt * 64) * 1024;

  // Q frags (S-phase B operand) live in registers
  const u16* Qrow = Qb + ((size_t)bh * 1024 + qt * 64 + qsb * 32 + l31) * 64;
  bfrag qf[4];
#pragma unroll
  for (int ko = 0; ko < 4; ++ko) qf[ko] = *(const bfrag*)(Qrow + ko * 16 + hi * 8);

  // mask tile (bf16 1.0/0.0) for denominator B-frags
  {
    int4 mi = *(const int4*)(mask + b * 1024 + t * 4);
    vshort4 mv;
    mv[0] = mi.x ? (short)0x3F80 : (short)0; mv[1] = mi.y ? (short)0x3F80 : (short)0;
    mv[2] = mi.z ? (short)0x3F80 : (short)0; mv[3] = mi.w ? (short)0x3F80 : (short)0;
    *(vshort4*)&Ms[t * 4] = mv;
  }

  auto stageK = [&](int kt) {
#pragma unroll
    for (int j = 0; j < 2; ++j) {
      const int c = w * 128 + j * 64 + lane;
      const int row = c >> 3, ck = (c & 7) ^ (row & 7);
      gll16(Kg + (size_t)(kt * 64 + row) * 64 + ck * 8,
            &Ks[(size_t)(w * 128 + j * 64) * 8]);
    }
  };
  auto stageV = [&](int kt) {
#pragma unroll
    for (int j = 0; j < 2; ++j) {
      const int c = w * 128 + j * 64 + lane;
      const int row = c >> 3, ck = (c & 7) ^ (row & 7);
      gll16(Vg + (size_t)row * 1024 + kt * 64 + ck * 8,
            &Vs[(size_t)(w * 128 + j * 64) * 8]);
    }
  };
  auto stageA = [&](int kt) {
#pragma unroll
    for (int j = 0; j < 2; ++j) {
      const int c = w * 128 + j * 64 + lane;
      const int row = c >> 3, ck = (c & 7) ^ (row & 7);
      gll16(Ag + (size_t)row * 1024 + kt * 64 + ck * 8,
            &Acts[(size_t)(w * 128 + j * 64) * 8]);
    }
  };

  stageK(0); stageV(0); stageA(0);
  __syncthreads();

  ffrag16 accE = {0.f}, accG = {0.f}, dacc = {0.f};
#pragma unroll
  for (int i = 0; i < 16; ++i) { accE[i] = 0.f; accG[i] = 0.f; dacc[i] = 0.f; }

  for (int kt = 0; kt < 16; ++kt) {
    // ---- S-phase: S^T block (m = k-local, n = q-local) ----
    ffrag16 st;
#pragma unroll
    for (int i = 0; i < 16; ++i) st[i] = 0.f;
    const int krow = msb * 32 + l31;
    const int kx7 = krow & 7;
#pragma unroll
    for (int ko = 0; ko < 4; ++ko) {
      bfrag ak = *(const bfrag*)&Ks[krow * 64 + (((ko * 2 + hi) ^ kx7) << 3)];
      st = __builtin_amdgcn_mfma_f32_32x32x16_bf16(ak, qf[ko], st, 0, 0, 0);
    }
    // ---- nonlinearity: E = exp(tanh(s/8)-1) = exp2(-2log2e/(exp2(s*log2e/4)+1))
    const int qrow = qsb * 32 + l31;
    const int qx7 = qrow & 7;
#pragma unroll
    for (int g = 0; g < 4; ++g) {
      float ee[4];
#pragma unroll
      for (int r = 0; r < 4; ++r) {
        const float tt = EXP2F(st[4 * g + r] * 0.360673760222f);
        ee[r] = EXP2F(RCPF(tt + 1.0f) * -2.88539008178f);
      }
      const int k0 = msb * 32 + g * 8 + hi * 4;
      *(uint2*)&Es[qrow * 64 + (((k0 >> 3) ^ qx7) << 3) + (k0 & 7)] =
          make_uint2(pk2(ee[0], ee[1]), pk2(ee[2], ee[3]));
    }
    __syncthreads();                   // Es visible; Ks reads done
    if (kt < 15) stageK(kt + 1);       // drains at next barrier (PV covers it)

    // ---- PV-phase: AE += E@V ; AG += act@V ; denom via mask B-frags ----
    const int erow = qpb * 32 + l31;
    const int ex7 = erow & 7;
    const int vrow = dpb * 32 + l31;
    const int vx7 = vrow & 7;
#pragma unroll
    for (int ko = 0; ko < 4; ++ko) {
      const int ecs = ((ko * 2 + hi) ^ ex7) << 3;
      const int vcs = ((ko * 2 + hi) ^ vx7) << 3;
      bfrag ea = *(const bfrag*)&Es[erow * 64 + ecs];
      bfrag bv = *(const bfrag*)&Vs[vrow * 64 + vcs];
      accE = __builtin_amdgcn_mfma_f32_32x32x16_bf16(ea, bv, accE, 0, 0, 0);
      bfrag aa = *(const bfrag*)&Acts[erow * 64 + ecs];
      accG = __builtin_amdgcn_mfma_f32_32x32x16_bf16(aa, bv, accG, 0, 0, 0);
      if (w < 2) {
        bfrag bm = *(const bfrag*)&Ms[kt * 64 + ko * 16 + hi * 8];
        dacc = __builtin_amdgcn_mfma_f32_32x32x16_bf16(ea, bm, dacc, 0, 0, 0);
      }
    }
    __syncthreads();                   // all Vs/Acts/Es reads done
    if (kt < 15) { stageV(kt + 1); stageA(kt + 1); }  // drains at next barrier1
  }

  // ---- epilogue: AE/AG bf16 stores (C-layout: col=lane&31, row from reg) ----
  const size_t obase = ((size_t)b * 1024 + qt * 64 + qpb * 32) * 512
                       + h * 64 + dpb * 32 + l31;
#pragma unroll
  for (int r = 0; r < 16; ++r) {
    const int qloc = (r & 3) + 8 * (r >> 2) + 4 * hi;
    AEb[obase + (size_t)qloc * 512] = f2b(accE[r]);
    AGb[obase + (size_t)qloc * 512] = f2b(accG[r]);
  }
  // ---- denominator reduce: cols identical; lanes 0,32 of waves 0,1 ----
  float dsumv = 0.0f;
  if (l31 == 0 && w < 2) {
    const int qb0 = b * 1024 + qt * 64 + qpb * 32 + 4 * hi;
#pragma unroll
    for (int r = 0; r < 16; ++r) {
      const int q = qb0 + (r & 3) + 8 * (r >> 2);
      dsumv += mask[q] ? dacc[r] : 0.0f;
    }
  }
  float* red4 = (float*)Es;
  if (l31 == 0 && w < 2) red4[w * 2 + hi] = dsumv;
  __syncthreads();
  if (t == 0) atomicAdd(denom + b, red4[0] + red4[1] + red4[2] + red4[3]);
}

// ---- out = (mq*(c1*AEb + c2*AGb)) @ Wo^T ------------------------------------
__global__ __launch_bounds__(256) void o_proj_k(
    const u16* __restrict__ AEb, const u16* __restrict__ AGb,
    const int* __restrict__ mask, const float* __restrict__ sums,
    const u16* __restrict__ Wb, float* __restrict__ out) {
  const int m0 = blockIdx.x * 128;
  const int n0 = blockIdx.y * 64;
  const int b = m0 >> 10;
  const float c1 = 0.5f / fmaxf(sums[b], TINYF);
  const float c2 = 0.5f / fmaxf(sums[8 + b], TINYF);
  __shared__ __align__(16) u16 As[128 * 64];
  __shared__ __align__(16) u16 Bs[64 * 64];
  const int t = threadIdx.x, w = t >> 6, lane = t & 63;
  const int l15 = lane & 15, quad = lane >> 4;
  const int x7 = l15 & 7;
  // per-chunk row constants (rows fixed across kk)
  int rowi[4]; float c1r[4], c2r[4];
#pragma unroll
  for (int i = 0; i < 4; ++i) {
    const int c = t + i * 256;
    rowi[i] = c >> 3;
    const int mq = mask[b * 1024 + ((m0 + rowi[i]) & 1023)];
    c1r[i] = mq ? c1 : 0.0f;
    c2r[i] = mq ? c2 : 0.0f;
  }
  const ffrag fz = {0.f, 0.f, 0.f, 0.f};
  ffrag acc[2][4];
#pragma unroll
  for (int am = 0; am < 2; ++am)
#pragma unroll
    for (int bn = 0; bn < 4; ++bn) acc[am][bn] = fz;

  for (int kk = 0; kk < 512; kk += 64) {
    __syncthreads();
#pragma unroll
    for (int i = 0; i < 4; ++i) {
      const int c = t + i * 256;
      const int row = rowi[i], ck = c & 7;
      const size_t gofs = (size_t)(m0 + row) * 512 + kk + ck * 8;
      uint4 ua = *(const uint4*)(AEb + gofs);
      uint4 ug = *(const uint4*)(AGb + gofs);
      const float a1 = c1r[i], a2 = c2r[i];
      uint4 res;
      res.x = pk2(a1 * blo(ua.x) + a2 * blo(ug.x), a1 * bhi(ua.x) + a2 * bhi(ug.x));
      res.y = pk2(a1 * blo(ua.y) + a2 * blo(ug.y), a1 * bhi(ua.y) + a2 * bhi(ug.y));
      res.z = pk2(a1 * blo(ua.z) + a2 * blo(ug.z), a1 * bhi(ua.z) + a2 * bhi(ug.z));
      res.w = pk2(a1 * blo(ua.w) + a2 * blo(ug.w), a1 * bhi(ua.w) + a2 * bhi(ug.w));
      *(uint4*)&As[row * 64 + ((ck ^ (row & 7)) << 3)] = res;
    }
#pragma unroll
    for (int j = 0; j < 2; ++j) {
      const int c = w * 128 + j * 64 + lane;
      const int row = c >> 3, ck = (c & 7) ^ (row & 7);
      gll16(Wb + (size_t)(1536 + n0 + row) * 512 + kk + ck * 8,
            &Bs[(size_t)(w * 128 + j * 64) * 8]);
    }
    __syncthreads();
#pragma unroll
    for (int s = 0; s < 2; ++s) {
      const int co = ((quad + 4 * s) ^ x7) << 3;
      bfrag a0 = *(const bfrag*)&As[(w * 32 + l15) * 64 + co];
      bfrag a1 = *(const bfrag*)&As[(w * 32 + 16 + l15) * 64 + co];
#pragma unroll
      for (int bn = 0; bn < 4; ++bn) {
        bfrag bb = *(const bfrag*)&Bs[(bn * 16 + l15) * 64 + co];
        acc[0][bn] = __builtin_amdgcn_mfma_f32_16x16x32_bf16(a0, bb, acc[0][bn], 0, 0, 0);
        acc[1][bn] = __builtin_amdgcn_mfma_f32_16x16x32_bf16(a1, bb, acc[1][bn], 0, 0, 0);
      }
    }
  }
#pragma unroll
  for (int am = 0; am < 2; ++am) {
    const int mbase = m0 + w * 32 + am * 16 + quad * 4;
#pragma unroll
    for (int bn = 0; bn < 4; ++bn) {
      const int n = n0 + bn * 16 + l15;
#pragma unroll
      for (int r = 0; r < 4; ++r)
        out[(size_t)(mbase + r) * 512 + n] = acc[am][bn][r];
    }
  }
}

extern "C" void kernel_launch(void* const* d_in, const int* in_sizes, int n_in,
                              void* d_out, int out_size, void* d_ws, size_t ws_size,
                              hipStream_t stream) {
  const float* x  = (const float*)d_in[0];
  const int* mask = (const int*)d_in[1];
  const float* Wq = (const float*)d_in[2];
  const float* Wk = (const float*)d_in[3];
  const float* Wv = (const float*)d_in[4];
  const float* Wo = (const float*)d_in[5];
  const float* G  = (const float*)d_in[6];
  float* out = (float*)d_out;

  u16* xb   = (u16*)d_ws;                    // 8192*512
  u16* Wb   = xb + (size_t)8192 * 512;       // 2048*512
  u16* Qb   = Wb + (size_t)2048 * 512;       // QSZ
  u16* Kb   = Qb + QSZ;
  u16* Vtb  = Kb + QSZ;
  u16* actb = Vtb + QSZ;                     // 1024*1024
  u16* AEb  = actb + (size_t)1024 * 1024;    // B*L*E
  u16* AGb  = AEb + (size_t)B_ * L_ * E_;    // B*L*E
  float* R  = (float*)(AGb + (size_t)B_ * L_ * E_);  // 1024*8
  float* SUMS = R + 8192;                    // denom[8], gsums[8]

  prep_k<<<2560, 256, 0, stream>>>(x, Wq, Wk, Wv, Wo, xb, Wb, SUMS);
  softmax_g_k<<<1024, 256, 0, stream>>>(G, mask, actb, R);
  gsum_reduce_k<<<1, 256, 0, stream>>>(R, mask, SUMS);
  proj_k<<<dim3(64, 24), 256, 0, stream>>>(xb, Wb, mask, Qb, Kb, Vtb);
  attn_k<<<dim3(16, 64), 256, 0, stream>>>(Qb, Kb, Vtb, actb, mask, AEb, AGb, SUMS);
  o_proj_k<<<dim3(64, 8), 256, 0, stream>>>(AEb, AGb, mask, SUMS, Wb, out);
}